// Round 12
// baseline (574.519 us; speedup 1.0000x reference)
//
#include <hip/hip_runtime.h>
#include <hip/hip_bf16.h>

#define DMODEL 2048
#define HEADS 16
#define DK 128
#define BATCH 4
#define SEQ 2048
#define MROWS (BATCH * SEQ)  // 8192

typedef __attribute__((ext_vector_type(8))) short bf16x8;
typedef __attribute__((ext_vector_type(4))) short bf16x4;
typedef __attribute__((ext_vector_type(4))) float f32x4;
typedef __attribute__((ext_vector_type(16))) float f32x16;

static __device__ __forceinline__ short f2bf(float x) {
    __hip_bfloat16 h = __float2bfloat16(x);
    union { __hip_bfloat16 h; short s; } u;
    u.h = h;
    return u.s;
}

static __device__ __forceinline__ int cvt_pk_bf16(float lo, float hi) {
    int r;
    asm("v_cvt_pk_bf16_f32 %0, %1, %2" : "=v"(r) : "v"(lo), "v"(hi));
    return r;
}

static __device__ __forceinline__ float exp2_fast(float x) {
    float r;
    asm("v_exp_f32 %0, %1" : "=v"(r) : "v"(x));
    return r;
}

#define MFMA16(a, b, c) __builtin_amdgcn_mfma_f32_16x16x32_bf16((a), (b), (c), 0, 0, 0)
#define MFMA32(a, b, c) __builtin_amdgcn_mfma_f32_32x32x16_bf16((a), (b), (c), 0, 0, 0)

static __device__ __forceinline__ void load_lds16(const void* g, void* l) {
    __builtin_amdgcn_global_load_lds(
        (const __attribute__((address_space(1))) unsigned int*)g,
        (__attribute__((address_space(3))) unsigned int*)l, 16, 0, 0);
}

// ---------------------------------------------------------------------------
// fused fp32 -> bf16 convert for q,k,v (grid-stride, one launch)
// ---------------------------------------------------------------------------
__global__ __launch_bounds__(256) void cvt3_bf16(
    const float* __restrict__ i0, const float* __restrict__ i1,
    const float* __restrict__ i2, short* __restrict__ o0,
    short* __restrict__ o1, short* __restrict__ o2, int n8) {
    int i = blockIdx.x * blockDim.x + threadIdx.x;
    const int stride = gridDim.x * blockDim.x;
    for (; i < 3 * n8; i += stride) {
        const int which = i / n8;
        const int idx = i - which * n8;
        const float* in = which == 0 ? i0 : (which == 1 ? i1 : i2);
        short* out = which == 0 ? o0 : (which == 1 ? o1 : o2);
        f32x4 a = ((const f32x4*)in)[idx * 2];
        f32x4 b = ((const f32x4*)in)[idx * 2 + 1];
        bf16x8 o;
        o[0] = f2bf(a[0]); o[1] = f2bf(a[1]); o[2] = f2bf(a[2]); o[3] = f2bf(a[3]);
        o[4] = f2bf(b[0]); o[5] = f2bf(b[1]); o[6] = f2bf(b[2]); o[7] = f2bf(b[3]);
        ((bf16x8*)out)[idx] = o;
    }
}

// ---------------------------------------------------------------------------
// fused fp32 [K][N] -> bf16 [N][K] transpose+convert for 4 weights (z=which)
// ---------------------------------------------------------------------------
__global__ __launch_bounds__(256) void cvt_tr4(
    const float* __restrict__ w0, const float* __restrict__ w1,
    const float* __restrict__ w2, const float* __restrict__ w3,
    short* __restrict__ t0, short* __restrict__ t1,
    short* __restrict__ t2, short* __restrict__ t3) {
    __shared__ short t[64][72];
    const int which = blockIdx.z;
    const float* W = which == 0 ? w0 : (which == 1 ? w1 : (which == 2 ? w2 : w3));
    short* Wt = which == 0 ? t0 : (which == 1 ? t1 : (which == 2 ? t2 : t3));
    const int n0 = blockIdx.x * 64, k0 = blockIdx.y * 64;
    const int tid = threadIdx.x;
#pragma unroll
    for (int p = 0; p < 4; p++) {
        const int kr = p * 16 + (tid >> 4);
        const int nc = (tid & 15) * 4;
        f32x4 v = *(const f32x4*)&W[(size_t)(k0 + kr) * DMODEL + n0 + nc];
#pragma unroll
        for (int j = 0; j < 4; j++) t[nc + j][kr] = f2bf(v[j]);
    }
    __syncthreads();
    const int nr = tid >> 2, ch = (tid & 3) * 16;
    *(bf16x8*)&Wt[(size_t)(n0 + nr) * DMODEL + k0 + ch] = *(const bf16x8*)&t[nr][ch];
    *(bf16x8*)&Wt[(size_t)(n0 + nr) * DMODEL + k0 + ch + 8] = *(const bf16x8*)&t[nr][ch + 8];
}

// ---------------------------------------------------------------------------
// bf16 [MROWS][DMODEL] -> bf16 [DMODEL][MROWS] transpose (fallback path only)
// ---------------------------------------------------------------------------
__global__ __launch_bounds__(256) void tr_bf16(const short* __restrict__ in,
                                               short* __restrict__ out) {
    __shared__ short t[64][65];
    const int c0 = blockIdx.x * 64, r0 = blockIdx.y * 64;
    const int tid = threadIdx.x;
    const int row = tid >> 2, cb = (tid & 3) * 16;
    bf16x8 a = *(const bf16x8*)&in[(size_t)(r0 + row) * DMODEL + c0 + cb];
    bf16x8 b2 = *(const bf16x8*)&in[(size_t)(r0 + row) * DMODEL + c0 + cb + 8];
#pragma unroll
    for (int j = 0; j < 8; j++) { t[cb + j][row] = a[j]; t[cb + 8 + j][row] = b2[j]; }
    __syncthreads();
#pragma unroll
    for (int j = 0; j < 16; j++)
        out[(size_t)(c0 + row) * MROWS + r0 + cb + j] = t[row][cb + j];
}

// ---------------------------------------------------------------------------
// gemm10: 256x256 tile, BK=64, 8 waves (2Mx4N), double-buffered 128KB LDS,
// m201-style 8-phase / 2-K-tile schedule with TWO barriers per phase:
//   {ds_read slot | stage issue | [lgkmcnt(8)] | vmcnt(N) | barrier A |
//    lgkmcnt(0)+sched_barrier | 16 MFMA (setprio) | barrier B}
// ds_reads overlap other waves' previous-phase MFMA; counted vmcnt keeps 6-10
// loads in flight, never draining to 0 in the main loop.
// Stage ledger (iter it, tiles 2it/2it+1 in buf0/buf1):
//   p0:B1h0(2it+1) p1:B1h1 p2:A1h1 p3:A0h0(2it+2) p4:B0h0 p5:B0h1 p6:A0h1
//   p7:A1h0(2it+3).  vmcnt(6) at p0,p1,p3,p4,p5,p7 retires exactly the
//   distance-4 stage the NEXT phase's ds_read needs (verified per phase;
//   prologue=10 issues + vmcnt(6); peel uses 6,6,-,4,2,0).
// ---------------------------------------------------------------------------
static __device__ __forceinline__ void stageAu(const char* g, char* lds,
                                               int ro, int ktb, int tid, int wid) {
#pragma unroll
    for (int j = 0; j < 2; j++) {
        const int u = j * 64 + (tid >> 3);
        const int r = ((u & 63) | ((u >> 6) << 7)) + ro;      // per-lane src row
        const int rbase = wid * 8 + j * 128 + ro;             // wave-uniform dst row
        load_lds16(g + (size_t)r * (DMODEL * 2) + ktb + (((tid & 7) * 16) ^ ((r & 7) << 4)),
                   lds + rbase * 128);
    }
}

static __device__ __forceinline__ void stageBu(const char* g, char* lds,
                                               int ro, int ktb, int tid, int wid) {
#pragma unroll
    for (int j = 0; j < 2; j++) {
        const int u = j * 64 + (tid >> 3);
        const int r = ((u & 31) | ((u >> 5) << 6)) + ro;
        const int rbase = (wid & 3) * 8 + (j * 2 + (wid >> 2)) * 64 + ro;
        load_lds16(g + (size_t)r * (DMODEL * 2) + ktb + (((tid & 7) * 16) ^ ((r & 7) << 4)),
                   lds + rbase * 128);
    }
}

#define LOAD_AF(buf, mh)                                                          \
    _Pragma("unroll") for (int mi = 0; mi < 4; mi++)                              \
    _Pragma("unroll") for (int kk = 0; kk < 2; kk++)                              \
        af[mi][kk] = *(const bf16x8*)((const char*)Asl[buf] +                     \
            (wm * 128 + (mh) * 64 + mi * 16 + l15) * 128 + ((kk * 64 + fg) ^ fx));

#define LOAD_BF(dst, buf, nh)                                                     \
    _Pragma("unroll") for (int ni = 0; ni < 2; ni++)                              \
    _Pragma("unroll") for (int kk = 0; kk < 2; kk++)                              \
        dst[ni][kk] = *(const bf16x8*)((const char*)Bsl[buf] +                    \
            (wn * 64 + (nh) * 32 + ni * 16 + l15) * 128 + ((kk * 64 + fg) ^ fx));

#define MFMA_QUAD(mh, nh, bsrc)                                                   \
    __builtin_amdgcn_s_setprio(1);                                                \
    _Pragma("unroll") for (int mi = 0; mi < 4; mi++)                              \
    _Pragma("unroll") for (int ni = 0; ni < 2; ni++)                              \
    _Pragma("unroll") for (int kk = 0; kk < 2; kk++)                              \
        acc[(mh) * 4 + mi][(nh) * 2 + ni] =                                       \
            MFMA16(af[mi][kk], bsrc[ni][kk], acc[(mh) * 4 + mi][(nh) * 2 + ni]);  \
    __builtin_amdgcn_s_setprio(0);

#define WAITV(N)  asm volatile("s_waitcnt vmcnt(" #N ")" ::: "memory")
#define WAITL(N)  asm volatile("s_waitcnt lgkmcnt(" #N ")" ::: "memory")
#define BARRIER() __builtin_amdgcn_s_barrier()
#define SBAR()    __builtin_amdgcn_sched_barrier(0)

template <typename OT, bool TRANSV = false>
__global__ __launch_bounds__(512, 2) void gemm10(
    const short* __restrict__ A, const short* __restrict__ Bt,
    const float* __restrict__ bias, OT* __restrict__ C, float oscale) {
    __shared__ short Asl[2][256 * 64];
    __shared__ short Bsl[2][256 * 64];
    const int tid = threadIdx.x, lane = tid & 63, wid = tid >> 6;

    const int nwg = gridDim.x;
    const int bid = blockIdx.x;
    const int swz = (bid & 7) * (nwg >> 3) + (bid >> 3);
    const int bx = swz >> 5, by = swz & 31;
    const int row0 = by * 256, col0 = bx * 256;
    const int wm = wid >> 2, wn = wid & 3;

    const char* Ab = (const char*)A + (size_t)row0 * (DMODEL * 2);
    const char* Bb = (const char*)Bt + (size_t)col0 * (DMODEL * 2);

    const int l15 = lane & 15;
    const int fg = (lane >> 4) * 16;
    const int fx = (lane & 7) << 4;

    f32x4 acc[8][4] = {};
    bf16x8 af[4][2], bA[2][2], bB[2][2];

    char* As0 = (char*)Asl[0];
    char* As1 = (char*)Asl[1];
    char* Bs0 = (char*)Bsl[0];
    char* Bs1 = (char*)Bsl[1];

    // ---- prologue: u1..u5 = 10 loads; vmcnt(6) retires tile0 Ah0+Bh0 ----
    stageAu(Ab, As0, 0, 0, tid, wid);     // u1: A0h0 t0
    stageBu(Bb, Bs0, 0, 0, tid, wid);     // u2: B0h0 t0
    stageBu(Bb, Bs0, 32, 0, tid, wid);    // u3: B0h1 t0
    stageAu(Ab, As0, 64, 0, tid, wid);    // u4: A0h1 t0
    stageAu(Ab, As1, 0, 128, tid, wid);   // u5: A1h0 t1
    WAITV(6);
    BARRIER();
    SBAR();

    const int NIT = DMODEL / 128;  // 16 iterations of 2 K-tiles
    for (int it = 0; it < NIT - 1; it++) {
        const int t1b = (2 * it + 1) * 128;
        const int t2b = (2 * it + 2) * 128;
        const int t3b = (2 * it + 3) * 128;

        // p0: reads A0h0,B0h0 (12 ds); stage B1h0(t1)
        LOAD_AF(0, 0); LOAD_BF(bA, 0, 0);
        stageBu(Bb, Bs1, 0, t1b, tid, wid);
        WAITL(8); WAITV(6);
        BARRIER(); WAITL(0); SBAR();
        MFMA_QUAD(0, 0, bA);
        BARRIER();

        // p1: reads B0h1; stage B1h1(t1)
        LOAD_BF(bB, 0, 1);
        stageBu(Bb, Bs1, 32, t1b, tid, wid);
        WAITV(6);
        BARRIER(); WAITL(0); SBAR();
        MFMA_QUAD(0, 1, bB);
        BARRIER();

        // p2: reads A0h1; stage A1h1(t1)
        LOAD_AF(0, 1);
        stageAu(Ab, As1, 64, t1b, tid, wid);
        BARRIER(); WAITL(0); SBAR();
        MFMA_QUAD(1, 1, bB);
        BARRIER();

        // p3: no reads; stage A0h0(t2)
        stageAu(Ab, As0, 0, t2b, tid, wid);
        WAITV(6);
        BARRIER(); SBAR();
        MFMA_QUAD(1, 0, bA);
        BARRIER();

        // p4: reads A1h0,B1h0 (12 ds); stage B0h0(t2)
        LOAD_AF(1, 0); LOAD_BF(bA, 1, 0);
        stageBu(Bb, Bs0, 0, t2b, tid, wid);
        WAITL(8); WAITV(6);
        BARRIER(); WAITL(0); SBAR();
        MFMA_QUAD(0, 0, bA);
        BARRIER();

        // p5: reads B1h1; stage B0h1(t2)
        LOAD_BF(bB, 1, 1);
        stageBu(Bb, Bs0, 32, t2b, tid, wid);
        WAITV(6);
        BARRIER(); WAITL(0); SBAR();
        MFMA_QUAD(0, 1, bB);
        BARRIER();

        // p6: reads A1h1; stage A0h1(t2)
        LOAD_AF(1, 1);
        stageAu(Ab, As0, 64, t2b, tid, wid);
        BARRIER(); WAITL(0); SBAR();
        MFMA_QUAD(1, 1, bB);
        BARRIER();

        // p7: no reads; stage A1h0(t3)
        stageAu(Ab, As1, 0, t3b, tid, wid);
        WAITV(6);
        BARRIER(); SBAR();
        MFMA_QUAD(1, 0, bA);
        BARRIER();
    }

    // ---- peeled last iteration (tiles 30,31): stages p0-p2 only ----
    {
        const int t1b = (DMODEL / 64 - 1) * 128;  // tile 31

        // p0
        LOAD_AF(0, 0); LOAD_BF(bA, 0, 0);
        stageBu(Bb, Bs1, 0, t1b, tid, wid);
        WAITL(8); WAITV(6);
        BARRIER(); WAITL(0); SBAR();
        MFMA_QUAD(0, 0, bA);
        BARRIER();

        // p1
        LOAD_BF(bB, 0, 1);
        stageBu(Bb, Bs1, 32, t1b, tid, wid);
        WAITV(6);
        BARRIER(); WAITL(0); SBAR();
        MFMA_QUAD(0, 1, bB);
        BARRIER();

        // p2
        LOAD_AF(0, 1);
        stageAu(Ab, As1, 64, t1b, tid, wid);
        BARRIER(); WAITL(0); SBAR();
        MFMA_QUAD(1, 1, bB);
        BARRIER();

        // p3 (no stage)
        WAITV(4);
        BARRIER(); SBAR();
        MFMA_QUAD(1, 0, bA);
        BARRIER();

        // p4
        LOAD_AF(1, 0); LOAD_BF(bA, 1, 0);
        WAITL(8); WAITV(2);
        BARRIER(); WAITL(0); SBAR();
        MFMA_QUAD(0, 0, bA);
        BARRIER();

        // p5
        LOAD_BF(bB, 1, 1);
        WAITV(0);
        BARRIER(); WAITL(0); SBAR();
        MFMA_QUAD(0, 1, bB);
        BARRIER();

        // p6
        LOAD_AF(1, 1);
        BARRIER(); WAITL(0); SBAR();
        MFMA_QUAD(1, 1, bB);
        BARRIER();

        // p7
        MFMA_QUAD(1, 0, bA);
    }

    // ---- epilogue ----
#pragma unroll
    for (int n = 0; n < 4; n++) {
        const int col = col0 + wn * 64 + n * 16 + l15;
        const float bz = bias[col];
#pragma unroll
        for (int m = 0; m < 8; m++) {
            const int row4 = row0 + wm * 128 + m * 16 + (lane >> 4) * 4;
            if constexpr (TRANSV) {
                bf16x4 tv;
#pragma unroll
                for (int j = 0; j < 4; j++) tv[j] = f2bf((acc[m][n][j] + bz) * oscale);
                *(bf16x4*)&C[(size_t)col * MROWS + row4] = tv;
            } else {
#pragma unroll
                for (int j = 0; j < 4; j++) {
                    const float v = (acc[m][n][j] + bz) * oscale;
                    if constexpr (sizeof(OT) == 2)
                        C[(size_t)(row4 + j) * DMODEL + col] = (OT)f2bf(v);
                    else
                        C[(size_t)(row4 + j) * DMODEL + col] = (OT)v;
                }
            }
        }
    }
}

// ---------------------------------------------------------------------------
// Fallback GEMM (round-0): A fp32 or bf16, conversion in staging.
// ---------------------------------------------------------------------------
template <typename AT, typename OT>
__global__ __launch_bounds__(256) void gemm_kernel(
    const AT* __restrict__ A, const float* __restrict__ W,
    const float* __restrict__ bias, OT* __restrict__ C, float oscale) {
    const int K = DMODEL, N = DMODEL;
    __shared__ short As[128][40];
    __shared__ short Bs[128][40];
    const int tid = threadIdx.x;
    const int lane = tid & 63;
    const int wid = tid >> 6;
    const int wm = wid >> 1, wn = wid & 1;
    const int row0 = blockIdx.y * 128;
    const int col0 = blockIdx.x * 128;
    f32x4 acc[4][4] = {};
    const int a_row = tid >> 1;
    const int a_col = (tid & 1) * 16;
    const int b_n = (tid & 31) * 4;
    const int b_k = (tid >> 5) * 4;
    for (int k0 = 0; k0 < K; k0 += 32) {
        __syncthreads();
        {
            const AT* src = A + (size_t)(row0 + a_row) * K + k0 + a_col;
            if constexpr (sizeof(AT) == 4) {
                const float* sf = reinterpret_cast<const float*>(src);
                f32x4 v0 = *(const f32x4*)(sf + 0);
                f32x4 v1 = *(const f32x4*)(sf + 4);
                f32x4 v2 = *(const f32x4*)(sf + 8);
                f32x4 v3 = *(const f32x4*)(sf + 12);
                bf16x8 w0, w1;
                w0[0] = f2bf(v0[0]); w0[1] = f2bf(v0[1]); w0[2] = f2bf(v0[2]); w0[3] = f2bf(v0[3]);
                w0[4] = f2bf(v1[0]); w0[5] = f2bf(v1[1]); w0[6] = f2bf(v1[2]); w0[7] = f2bf(v1[3]);
                w1[0] = f2bf(v2[0]); w1[1] = f2bf(v2[1]); w1[2] = f2bf(v2[2]); w1[3] = f2bf(v2[3]);
                w1[4] = f2bf(v3[0]); w1[5] = f2bf(v3[1]); w1[6] = f2bf(v3[2]); w1[7] = f2bf(v3[3]);
                *(bf16x8*)&As[a_row][a_col + 0] = w0;
                *(bf16x8*)&As[a_row][a_col + 8] = w1;
            } else {
                const short* ss = reinterpret_cast<const short*>(src);
                *(bf16x8*)&As[a_row][a_col + 0] = *(const bf16x8*)(ss + 0);
                *(bf16x8*)&As[a_row][a_col + 8] = *(const bf16x8*)(ss + 8);
            }
        }
        {
            const float* w0p = W + (size_t)(k0 + b_k + 0) * N + col0 + b_n;
            f32x4 r0 = *(const f32x4*)(w0p);
            f32x4 r1 = *(const f32x4*)(w0p + N);
            f32x4 r2 = *(const f32x4*)(w0p + 2 * N);
            f32x4 r3 = *(const f32x4*)(w0p + 3 * N);
#pragma unroll
            for (int j = 0; j < 4; j++) {
                bf16x4 t;
                t[0] = f2bf(r0[j]); t[1] = f2bf(r1[j]); t[2] = f2bf(r2[j]); t[3] = f2bf(r3[j]);
                *(bf16x4*)&Bs[b_n + j][b_k] = t;
            }
        }
        __syncthreads();
        bf16x8 af[4], bfr[4];
#pragma unroll
        for (int m = 0; m < 4; m++)
            af[m] = *(const bf16x8*)&As[wm * 64 + m * 16 + (lane & 15)][(lane >> 4) * 8];
#pragma unroll
        for (int n = 0; n < 4; n++)
            bfr[n] = *(const bf16x8*)&Bs[wn * 64 + n * 16 + (lane & 15)][(lane >> 4) * 8];
#pragma unroll
        for (int m = 0; m < 4; m++)
#pragma unroll
            for (int n = 0; n < 4; n++)
                acc[m][n] = MFMA16(af[m], bfr[n], acc[m][n]);
    }
#pragma unroll
    for (int m = 0; m < 4; m++) {
#pragma unroll
        for (int n = 0; n < 4; n++) {
            const int col = col0 + wn * 64 + n * 16 + (lane & 15);
            const float bz = bias[col];
#pragma unroll
            for (int j = 0; j < 4; j++) {
                const int row = row0 + wm * 64 + m * 16 + (lane >> 4) * 4 + j;
                const float v = (acc[m][n][j] + bz) * oscale;
                if constexpr (sizeof(OT) == 2)
                    C[(size_t)row * N + col] = (OT)f2bf(v);
                else
                    C[(size_t)row * N + col] = (OT)v;
            }
        }
    }
}

// ---------------------------------------------------------------------------
// Flash attention v9 (unchanged): 8 waves, QBLK=256, KVBLK=128, in-register
// softmax, conflict-free swizzle, K/V^T via global_load_lds, kg-pipelined.
// ---------------------------------------------------------------------------
__global__ __launch_bounds__(512, 2) void attn_kernel(
    const short* __restrict__ Qp, const short* __restrict__ Kp,
    const short* __restrict__ Vtp, short* __restrict__ Oout) {
    const int nwg = gridDim.x;
    const int bid = blockIdx.x;
    const int bx = (bid & 7) * (nwg >> 3) + (bid >> 3);
    const int qt = bx & 7;            // SEQ/256 = 8
    const int h = (bx >> 3) & 15;
    const int b = bx >> 7;

    __shared__ short Ks[2][128 * 128];   // [key][d], 256B rows, XOR (key&15)<<4
    __shared__ short Vts[2][128 * 128];  // [d][key], 256B rows, XOR (d&15)<<4

    const int tid = threadIdx.x;
    const int lane = tid & 63;
    const int wid = tid >> 6;           // 0..7
    const int lo = lane & 31;
    const int hi1 = lane >> 5;

    bf16x8 qf[8];
    {
        const short* qrow = Qp + (size_t)(b * SEQ + qt * 256 + wid * 32 + lo) * DMODEL + h * DK;
#pragma unroll
        for (int dk = 0; dk < 8; dk++)
            qf[dk] = *(const bf16x8*)(qrow + dk * 16 + hi1 * 8);
    }

    f32x16 oacc[4] = {};
    float lsum = 0.f;

    const char* Kbase = (const char*)(Kp + (size_t)(b * SEQ) * DMODEL + h * DK);
    const char* Vtbase = (const char*)(Vtp + (size_t)(h * DK) * MROWS + b * SEQ);

    const int srow = wid * 16 + (lane >> 4);
    const int scp = (lane & 15) * 16;
    const int NT = SEQ / 128;                   // 16
    const float C12 = 17.3123404906676f;        // 12 * log2(e)

#pragma unroll
    for (int i = 0; i < 4; i++) {
        const int rr = srow + i * 4;
        load_lds16(Kbase + (size_t)rr * (DMODEL * 2) + (scp ^ ((rr & 15) << 4)),
                   (char*)Ks[0] + wid * 4096 + i * 1024);
    }
#pragma unroll
    for (int i = 0; i < 4; i++) {
        const int dd = srow + i * 4;
        load_lds16(Vtbase + (size_t)dd * (MROWS * 2) + (scp ^ ((dd & 15) << 4)),
                   (char*)Vts[0] + wid * 4096 + i * 1024);
    }
    asm volatile("s_waitcnt vmcnt(0)" ::: "memory");
    __builtin_amdgcn_s_barrier();
    __builtin_amdgcn_sched_barrier(0);

    for (int kt = 0; kt < NT; kt++) {
        const int cur = kt & 1;
        const bool more = (kt + 1) < NT;

        if (more) {
#pragma unroll
            for (int i = 0; i < 4; i++) {
                const int rr = srow + i * 4;
                load_lds16(Kbase + (size_t)((kt + 1) * 128 + rr) * (DMODEL * 2) + (scp ^ ((rr & 15) << 4)),
                           (char*)Ks[cur ^ 1] + wid * 4096 + i * 1024);
            }
#pragma unroll
            for (int i = 0; i < 4; i++) {
                const int dd = srow + i * 4;
                load_lds16(Vtbase + (size_t)dd * (MROWS * 2) + (kt + 1) * 256 + (scp ^ ((dd & 15) << 4)),
                           (char*)Vts[cur ^ 1] + wid * 4096 + i * 1024);
            }
        }

        f32x16 sc[2];
        bf16x8 pa[8];

        sc[0] = (f32x16){};
        __builtin_amdgcn_s_setprio(1);
#pragma unroll
        for (int dk = 0; dk < 8; dk++) {
            const int r = 0 * 32 + lo;
            const int cb = (dk * 32 + hi1 * 16) ^ ((r & 15) << 4);
            bf16x8 kf = *(const bf16x8*)((char*)Ks[cur] + r * 256 + cb);
            sc[0] = MFMA32(kf, qf[dk], sc[0]);
        }
        __builtin_amdgcn_s_setprio(0);

#pragma unroll
        for (int g = 0; g < 4; g++) {
            if (g < 3) {
                sc[(g + 1) & 1] = (f32x16){};
                __builtin_amdgcn_s_setprio(1);
#pragma unroll
                for (int dk = 0; dk < 8; dk++) {
                    const int r = (g + 1) * 32 + lo;
                    const int cb = (dk * 32 + hi1 * 16) ^ ((r & 15) << 4);
                    bf16x8 kf = *(const bf16x8*)((char*)Ks[cur] + r * 256 + cb);
                    sc[(g + 1) & 1] = MFMA32(kf, qf[dk], sc[(g + 1) & 1]);
                }
                __builtin_amdgcn_s_setprio(0);
            }
            {
                f32x16& s = sc[g & 1];
#pragma unroll
                for (int r = 0; r < 16; r++)
                    s[r] = exp2_fast(s[r] - C12);
                float s0 = 0.f, s1 = 0.f, s2 = 0.f, s3 = 0.f;
#pragma unroll
                for (int r = 0; r < 16; r += 4) {
                    s0 += s[r]; s1 += s[r + 1]; s2 += s[r + 2]; s3 += s[r + 3];
                }
                lsum += (s0 + s1) + (s2 + s3);
#pragma unroll
                for (int hf = 0; hf < 2; hf++) {
                    const int X0 = cvt_pk_bf16(s[8 * hf + 0], s[8 * hf + 1]);
                    const int X1 = cvt_pk_bf16(s[8 * hf + 2], s[8 * hf + 3]);
                    const int X2 = cvt_pk_bf16(s[8 * hf + 4], s[8 * hf + 5]);
                    const int X3 = cvt_pk_bf16(s[8 * hf + 6], s[8 * hf + 7]);
                    const int L0 = hi1 ? X2 : X0, L1 = hi1 ? X3 : X1;
                    const int S0 = hi1 ? X0 : X2, S1 = hi1 ? X1 : X3;
                    const int R0 = __shfl_xor(S0, 32, 64);
                    const int R1 = __shfl_xor(S1, 32, 64);
                    union { int i[4]; bf16x8 v; } u;
                    u.i[0] = hi1 ? R0 : L0;
                    u.i[1] = hi1 ? R1 : L1;
                    u.i[2] = hi1 ? L0 : R0;
                    u.i[3] = hi1 ? L1 : R1;
                    pa[2 * g + hf] = u.v;
                }
            }
        }

        __builtin_amdgcn_s_setprio(1);
#pragma unroll
        for (int ks = 0; ks < 8; ks++) {
#pragma unroll
            for (int n = 0; n < 4; n++) {
                const int d = n * 32 + lo;
                const int cb = (ks * 32 + hi1 * 16) ^ ((d & 15) << 4);
                bf16x8 vf = *(const bf16x8*)((char*)Vts[cur] + d * 256 + cb);
                oacc[n] = MFMA32(vf, pa[ks], oacc[n]);
            }
        }
        __builtin_amdgcn_s_setprio(0);

        if (more) {
            asm volatile("s_waitcnt vmcnt(0)" ::: "memory");
            asm volatile("s_waitcnt lgkmcnt(0)" ::: "memory");
            __builtin_amdgcn_s_barrier();
            __builtin_amdgcn_sched_barrier(0);
        }
    }

    const float l = lsum + __shfl_xor(lsum, 32, 64);
    const float inv = 1.0f / l;
    short* obase = Oout + (size_t)(b * SEQ + qt * 256 + wid * 32 + lo) * DMODEL + h * DK;
#pragma unroll
    for (int n = 0; n < 4; n++) {
#pragma unroll
        for (int rr = 0; rr < 8; rr++) {
            const int d = n * 32 + 2 * (rr & 1) + 8 * (rr >> 1) + 4 * hi1;
            const int pkv = cvt_pk_bf16(oacc[n][2 * rr] * inv, oacc[n][2 * rr + 1] * inv);
            *(int*)(obase + d) = pkv;
        }
    }
}

// ---------------------------------------------------------------------------
extern "C" void kernel_launch(void* const* d_in, const int* in_sizes, int n_in,
                              void* d_out, int out_size, void* d_ws, size_t ws_size,
                              hipStream_t stream) {
    const float* q   = (const float*)d_in[0];
    const float* k   = (const float*)d_in[1];
    const float* v   = (const float*)d_in[2];
    const float* w_q = (const float*)d_in[3];
    const float* b_q = (const float*)d_in[4];
    const float* w_k = (const float*)d_in[5];
    const float* b_k = (const float*)d_in[6];
    const float* w_v = (const float*)d_in[7];
    const float* b_v = (const float*)d_in[8];
    const float* w_o = (const float*)d_in[9];
    const float* b_o = (const float*)d_in[10];
    float* out = (float*)d_out;

    const size_t PROJ = (size_t)MROWS * DMODEL;
    const size_t WSZ = (size_t)DMODEL * DMODEL;
    // 1/sqrt(128) * log2(e): exp2-based softmax
    const float qscale = 0.08838834764831845f * 1.4426950408889634f;
    const int attn_grid = BATCH * HEADS * (SEQ / 256);  // 512

    if (ws_size >= (6 * PROJ + 4 * WSZ) * sizeof(short)) {
        short* qbf = (short*)d_ws;
        short* kbf = qbf + PROJ;
        short* vbf = kbf + PROJ;
        short* Qp  = vbf + PROJ;
        short* Kp  = Qp + PROJ;
        short* Vt  = Kp + PROJ;   // V^T [DMODEL][MROWS]
        short* wtq = Vt + PROJ;
        short* wtk = wtq + WSZ;
        short* wtv = wtk + WSZ;
        short* wto = wtv + WSZ;
        short* Ao  = qbf;  // reuse (qbf dead after Q projection)

        const int n8 = (int)(PROJ / 8);
        cvt3_bf16<<<3072, 256, 0, stream>>>(q, k, v, qbf, kbf, vbf, n8);
        dim3 gtr(DMODEL / 64, DMODEL / 64, 4);
        cvt_tr4<<<gtr, 256, 0, stream>>>(w_q, w_k, w_v, w_o, wtq, wtk, wtv, wto);

        const int nwg8 = (MROWS / 256) * (DMODEL / 256);  // 256
        gemm10<short><<<nwg8, 512, 0, stream>>>(qbf, wtq, b_q, Qp, qscale);
        gemm10<short><<<nwg8, 512, 0, stream>>>(kbf, wtk, b_k, Kp, 1.0f);
        gemm10<short, true><<<nwg8, 512, 0, stream>>>(vbf, wtv, b_v, Vt, 1.0f);

        attn_kernel<<<attn_grid, 512, 0, stream>>>(Qp, Kp, Vt, Ao);

        gemm10<float><<<nwg8, 512, 0, stream>>>(Ao, wto, b_o, out, 1.0f);
    } else {
        // fallback: 5 x PROJ layout (Qp,Kp,Vp,Vt,Ao)
        short* Qp = (short*)d_ws;
        short* Kp = Qp + PROJ;
        short* Vp = Kp + PROJ;
        short* Vt = Vp + PROJ;
        short* Ao = Vt + PROJ;
        dim3 gblk(DMODEL / 128, MROWS / 128);
        gemm_kernel<float, short><<<gblk, 256, 0, stream>>>(q, w_q, b_q, Qp, qscale);
        gemm_kernel<float, short><<<gblk, 256, 0, stream>>>(k, w_k, b_k, Kp, 1.0f);
        gemm_kernel<float, short><<<gblk, 256, 0, stream>>>(v, w_v, b_v, Vp, 1.0f);
        dim3 gtrv(DMODEL / 64, MROWS / 64);
        tr_bf16<<<gtrv, 256, 0, stream>>>(Vp, Vt);
        attn_kernel<<<attn_grid, 512, 0, stream>>>(Qp, Kp, Vt, Ao);
        gemm_kernel<short, float><<<gblk, 256, 0, stream>>>(Ao, w_o, b_o, out, 1.0f);
    }
}

// Round 13
// 536.057 us; speedup vs baseline: 1.0718x; 1.0718x over previous
//
#include <hip/hip_runtime.h>
#include <hip/hip_bf16.h>

#define DMODEL 2048
#define HEADS 16
#define DK 128
#define BATCH 4
#define SEQ 2048
#define MROWS (BATCH * SEQ)  // 8192

typedef __attribute__((ext_vector_type(8))) short bf16x8;
typedef __attribute__((ext_vector_type(4))) short bf16x4;
typedef __attribute__((ext_vector_type(4))) float f32x4;
typedef __attribute__((ext_vector_type(16))) float f32x16;

static __device__ __forceinline__ short f2bf(float x) {
    __hip_bfloat16 h = __float2bfloat16(x);
    union { __hip_bfloat16 h; short s; } u;
    u.h = h;
    return u.s;
}

static __device__ __forceinline__ int cvt_pk_bf16(float lo, float hi) {
    int r;
    asm("v_cvt_pk_bf16_f32 %0, %1, %2" : "=v"(r) : "v"(lo), "v"(hi));
    return r;
}

static __device__ __forceinline__ float exp2_fast(float x) {
    float r;
    asm("v_exp_f32 %0, %1" : "=v"(r) : "v"(x));
    return r;
}

#define MFMA16(a, b, c) __builtin_amdgcn_mfma_f32_16x16x32_bf16((a), (b), (c), 0, 0, 0)
#define MFMA32(a, b, c) __builtin_amdgcn_mfma_f32_32x32x16_bf16((a), (b), (c), 0, 0, 0)

static __device__ __forceinline__ void load_lds16(const void* g, void* l) {
    __builtin_amdgcn_global_load_lds(
        (const __attribute__((address_space(1))) unsigned int*)g,
        (__attribute__((address_space(3))) unsigned int*)l, 16, 0, 0);
}

// ---------------------------------------------------------------------------
// fused fp32 -> bf16 convert for q,k,v (grid-stride, one launch)
// ---------------------------------------------------------------------------
__global__ __launch_bounds__(256) void cvt3_bf16(
    const float* __restrict__ i0, const float* __restrict__ i1,
    const float* __restrict__ i2, short* __restrict__ o0,
    short* __restrict__ o1, short* __restrict__ o2, int n8) {
    int i = blockIdx.x * blockDim.x + threadIdx.x;
    const int stride = gridDim.x * blockDim.x;
    for (; i < 3 * n8; i += stride) {
        const int which = i / n8;
        const int idx = i - which * n8;
        const float* in = which == 0 ? i0 : (which == 1 ? i1 : i2);
        short* out = which == 0 ? o0 : (which == 1 ? o1 : o2);
        f32x4 a = ((const f32x4*)in)[idx * 2];
        f32x4 b = ((const f32x4*)in)[idx * 2 + 1];
        bf16x8 o;
        o[0] = f2bf(a[0]); o[1] = f2bf(a[1]); o[2] = f2bf(a[2]); o[3] = f2bf(a[3]);
        o[4] = f2bf(b[0]); o[5] = f2bf(b[1]); o[6] = f2bf(b[2]); o[7] = f2bf(b[3]);
        ((bf16x8*)out)[idx] = o;
    }
}

// ---------------------------------------------------------------------------
// fused fp32 [K][N] -> bf16 [N][K] transpose+convert for 4 weights (z=which)
// ---------------------------------------------------------------------------
__global__ __launch_bounds__(256) void cvt_tr4(
    const float* __restrict__ w0, const float* __restrict__ w1,
    const float* __restrict__ w2, const float* __restrict__ w3,
    short* __restrict__ t0, short* __restrict__ t1,
    short* __restrict__ t2, short* __restrict__ t3) {
    __shared__ short t[64][72];
    const int which = blockIdx.z;
    const float* W = which == 0 ? w0 : (which == 1 ? w1 : (which == 2 ? w2 : w3));
    short* Wt = which == 0 ? t0 : (which == 1 ? t1 : (which == 2 ? t2 : t3));
    const int n0 = blockIdx.x * 64, k0 = blockIdx.y * 64;
    const int tid = threadIdx.x;
#pragma unroll
    for (int p = 0; p < 4; p++) {
        const int kr = p * 16 + (tid >> 4);
        const int nc = (tid & 15) * 4;
        f32x4 v = *(const f32x4*)&W[(size_t)(k0 + kr) * DMODEL + n0 + nc];
#pragma unroll
        for (int j = 0; j < 4; j++) t[nc + j][kr] = f2bf(v[j]);
    }
    __syncthreads();
    const int nr = tid >> 2, ch = (tid & 3) * 16;
    *(bf16x8*)&Wt[(size_t)(n0 + nr) * DMODEL + k0 + ch] = *(const bf16x8*)&t[nr][ch];
    *(bf16x8*)&Wt[(size_t)(n0 + nr) * DMODEL + k0 + ch + 8] = *(const bf16x8*)&t[nr][ch + 8];
}

// ---------------------------------------------------------------------------
// bf16 [MROWS][DMODEL] -> bf16 [DMODEL][MROWS] transpose (fallback path only)
// ---------------------------------------------------------------------------
__global__ __launch_bounds__(256) void tr_bf16(const short* __restrict__ in,
                                               short* __restrict__ out) {
    __shared__ short t[64][65];
    const int c0 = blockIdx.x * 64, r0 = blockIdx.y * 64;
    const int tid = threadIdx.x;
    const int row = tid >> 2, cb = (tid & 3) * 16;
    bf16x8 a = *(const bf16x8*)&in[(size_t)(r0 + row) * DMODEL + c0 + cb];
    bf16x8 b2 = *(const bf16x8*)&in[(size_t)(r0 + row) * DMODEL + c0 + cb + 8];
#pragma unroll
    for (int j = 0; j < 8; j++) { t[cb + j][row] = a[j]; t[cb + 8 + j][row] = b2[j]; }
    __syncthreads();
#pragma unroll
    for (int j = 0; j < 16; j++)
        out[(size_t)(c0 + row) * MROWS + r0 + cb + j] = t[row][cb + j];
}

// ---------------------------------------------------------------------------
// gemm8 core (the verified 4-phase 256x256 schedule): BK=64, 8 waves (2Mx4N),
// single 64KB LDS buffer, counted vmcnt, region-rotated staging. LDS passed
// in from the kernel so the fused-QKV variant keeps 64KB (2 blocks/CU).
// transv: write output transposed ([col][row], for V^T) as packed 8B rows.
// ---------------------------------------------------------------------------
static __device__ __forceinline__ void stage2(const char* gbase, char* lbase,
                                              int rb, int r8, int scol, int ktb) {
#pragma unroll
    for (int i = 0; i < 2; i++)
        load_lds16(gbase + (size_t)(rb + i * 8 + r8) * (DMODEL * 2) + ktb + scol,
                   lbase + (rb + i * 8) * 128);
}

template <typename OT>
static __device__ __forceinline__ void gemm8_impl(
    char* Asl, char* Bsl,
    const short* __restrict__ A, const short* __restrict__ Bt,
    const float* __restrict__ bias, OT* __restrict__ C,
    float oscale, bool transv, int bx, int by) {
    const int tid = threadIdx.x, lane = tid & 63, wid = tid >> 6;
    const int row0 = by * 256, col0 = bx * 256;
    const int wm = wid >> 2, wn = wid & 3;

    const int r8 = lane >> 3;
    const int scol = ((lane & 7) * 16) ^ (r8 << 4);
    const int a1r = ((wid & 4) << 5) + (wid & 3) * 16;
    const int b1r = (wid >> 1) * 64 + (wid & 1) * 16;

    const char* Ab = (const char*)A + (size_t)row0 * (DMODEL * 2);
    const char* Bb = (const char*)Bt + (size_t)col0 * (DMODEL * 2);

    const int arow = wm * 128 + (lane & 15);
    const int brow = wn * 64 + (lane & 15);
    const int fg = (lane >> 4) * 16;
    const int fx = (lane & 7) << 4;

    f32x4 acc[8][4] = {};
    bf16x8 af[4][2], bfr[4][2];

    const int NT = DMODEL / 64;

    stage2(Ab, Asl, a1r, r8, scol, 0);
    stage2(Bb, Bsl, b1r, r8, scol, 0);
    stage2(Bb, Bsl, b1r + 32, r8, scol, 0);
    stage2(Ab, Asl, a1r + 64, r8, scol, 0);

    for (int t = 0; t < NT; t++) {
        const bool more = (t + 1) < NT;
        const int ktb = (t + 1) * 128;

        // phase 0
        asm volatile("s_waitcnt vmcnt(4)" ::: "memory");
        asm volatile("s_waitcnt lgkmcnt(0)" ::: "memory");
        __builtin_amdgcn_s_barrier();
        __builtin_amdgcn_sched_barrier(0);
#pragma unroll
        for (int m = 0; m < 4; m++)
#pragma unroll
            for (int kk = 0; kk < 2; kk++)
                af[m][kk] = *(const bf16x8*)(Asl + (arow + m * 16) * 128 + ((kk * 64 + fg) ^ fx));
#pragma unroll
        for (int n = 0; n < 2; n++)
#pragma unroll
            for (int kk = 0; kk < 2; kk++)
                bfr[n][kk] = *(const bf16x8*)(Bsl + (brow + n * 16) * 128 + ((kk * 64 + fg) ^ fx));
        __builtin_amdgcn_s_setprio(1);
#pragma unroll
        for (int m = 0; m < 4; m++)
#pragma unroll
            for (int n = 0; n < 2; n++)
#pragma unroll
                for (int kk = 0; kk < 2; kk++)
                    acc[m][n] = MFMA16(af[m][kk], bfr[n][kk], acc[m][n]);
        __builtin_amdgcn_s_setprio(0);

        // phase 1
        asm volatile("s_waitcnt vmcnt(2)" ::: "memory");
        asm volatile("s_waitcnt lgkmcnt(0)" ::: "memory");
        __builtin_amdgcn_s_barrier();
        __builtin_amdgcn_sched_barrier(0);
#pragma unroll
        for (int n = 2; n < 4; n++)
#pragma unroll
            for (int kk = 0; kk < 2; kk++)
                bfr[n][kk] = *(const bf16x8*)(Bsl + (brow + n * 16) * 128 + ((kk * 64 + fg) ^ fx));
        if (more) {
            stage2(Ab, Asl, a1r, r8, scol, ktb);
            stage2(Bb, Bsl, b1r, r8, scol, ktb);
        }
        __builtin_amdgcn_s_setprio(1);
#pragma unroll
        for (int m = 0; m < 4; m++)
#pragma unroll
            for (int n = 2; n < 4; n++)
#pragma unroll
                for (int kk = 0; kk < 2; kk++)
                    acc[m][n] = MFMA16(af[m][kk], bfr[n][kk], acc[m][n]);
        __builtin_amdgcn_s_setprio(0);

        // phase 2
        if (more) asm volatile("s_waitcnt vmcnt(4)" ::: "memory");
        else      asm volatile("s_waitcnt vmcnt(0)" ::: "memory");
        asm volatile("s_waitcnt lgkmcnt(0)" ::: "memory");
        __builtin_amdgcn_s_barrier();
        __builtin_amdgcn_sched_barrier(0);
#pragma unroll
        for (int mi = 0; mi < 4; mi++)
#pragma unroll
            for (int kk = 0; kk < 2; kk++)
                af[mi][kk] = *(const bf16x8*)(Asl + (arow + 64 + mi * 16) * 128 + ((kk * 64 + fg) ^ fx));
        if (more) stage2(Bb, Bsl, b1r + 32, r8, scol, ktb);
        __builtin_amdgcn_s_setprio(1);
#pragma unroll
        for (int mi = 0; mi < 4; mi++)
#pragma unroll
            for (int n = 2; n < 4; n++)
#pragma unroll
                for (int kk = 0; kk < 2; kk++)
                    acc[4 + mi][n] = MFMA16(af[mi][kk], bfr[n][kk], acc[4 + mi][n]);
        __builtin_amdgcn_s_setprio(0);

        // phase 3
        asm volatile("s_waitcnt lgkmcnt(0)" ::: "memory");
        __builtin_amdgcn_s_barrier();
        __builtin_amdgcn_sched_barrier(0);
        if (more) stage2(Ab, Asl, a1r + 64, r8, scol, ktb);
        __builtin_amdgcn_s_setprio(1);
#pragma unroll
        for (int mi = 0; mi < 4; mi++)
#pragma unroll
            for (int n = 0; n < 2; n++)
#pragma unroll
                for (int kk = 0; kk < 2; kk++)
                    acc[4 + mi][n] = MFMA16(af[mi][kk], bfr[n][kk], acc[4 + mi][n]);
        __builtin_amdgcn_s_setprio(0);
    }

    // ---- epilogue ----
#pragma unroll
    for (int n = 0; n < 4; n++) {
        const int col = col0 + wn * 64 + n * 16 + (lane & 15);
        const float bz = bias[col];
#pragma unroll
        for (int m = 0; m < 8; m++) {
            const int row4 = row0 + wm * 128 + m * 16 + (lane >> 4) * 4;
            if (transv) {
                bf16x4 tv;
#pragma unroll
                for (int j = 0; j < 4; j++) tv[j] = f2bf((acc[m][n][j] + bz) * oscale);
                *(bf16x4*)&((short*)C)[(size_t)col * MROWS + row4] = tv;
            } else {
#pragma unroll
                for (int j = 0; j < 4; j++) {
                    const float v = (acc[m][n][j] + bz) * oscale;
                    if constexpr (sizeof(OT) == 2)
                        C[(size_t)(row4 + j) * DMODEL + col] = (OT)f2bf(v);
                    else
                        C[(size_t)(row4 + j) * DMODEL + col] = (OT)v;
                }
            }
        }
    }
}

// single-GEMM launcher (O projection): grid 256
template <typename OT>
__global__ __launch_bounds__(512, 2) void gemm8_one(
    const short* __restrict__ A, const short* __restrict__ Bt,
    const float* __restrict__ bias, OT* __restrict__ C, float oscale) {
    __shared__ short Asl[256 * 64];
    __shared__ short Bsl[256 * 64];
    const int nwg = gridDim.x;
    const int bid = blockIdx.x;
    const int swz = (bid & 7) * (nwg >> 3) + (bid >> 3);
    const int bx = swz >> 5, by = swz & 31;
    gemm8_impl<OT>((char*)Asl, (char*)Bsl, A, Bt, bias, C, oscale, false, bx, by);
}

// fused QKV launcher: grid 768 = 3 x 256; 2 blocks/CU resident -> the two
// co-scheduled blocks' waves hide each other's barrier/drain stalls (m114).
__global__ __launch_bounds__(512, 2) void gemm8_qkv(
    const short* __restrict__ qA, const short* __restrict__ kA,
    const short* __restrict__ vA, const short* __restrict__ wq,
    const short* __restrict__ wk, const short* __restrict__ wv,
    const float* __restrict__ bq, const float* __restrict__ bk,
    const float* __restrict__ bv, short* __restrict__ Qp,
    short* __restrict__ Kp, short* __restrict__ Vt, float qscale) {
    __shared__ short Asl[256 * 64];
    __shared__ short Bsl[256 * 64];
    const int bid = blockIdx.x;
    const int which = bid >> 8;       // 0=q 1=k 2=v
    const int lb = bid & 255;
    const int swz = (lb & 7) * 32 + (lb >> 3);
    const int bx = swz >> 5, by = swz & 31;
    const short* A = which == 0 ? qA : (which == 1 ? kA : vA);
    const short* Bt = which == 0 ? wq : (which == 1 ? wk : wv);
    const float* bias = which == 0 ? bq : (which == 1 ? bk : bv);
    short* C = which == 0 ? Qp : (which == 1 ? Kp : Vt);
    const float os = which == 0 ? qscale : 1.0f;
    gemm8_impl<short>((char*)Asl, (char*)Bsl, A, Bt, bias, C, os, which == 2, bx, by);
}

// ---------------------------------------------------------------------------
// Fallback GEMM (round-0): A fp32 or bf16, conversion in staging.
// ---------------------------------------------------------------------------
template <typename AT, typename OT>
__global__ __launch_bounds__(256) void gemm_kernel(
    const AT* __restrict__ A, const float* __restrict__ W,
    const float* __restrict__ bias, OT* __restrict__ C, float oscale) {
    const int K = DMODEL, N = DMODEL;
    __shared__ short As[128][40];
    __shared__ short Bs[128][40];
    const int tid = threadIdx.x;
    const int lane = tid & 63;
    const int wid = tid >> 6;
    const int wm = wid >> 1, wn = wid & 1;
    const int row0 = blockIdx.y * 128;
    const int col0 = blockIdx.x * 128;
    f32x4 acc[4][4] = {};
    const int a_row = tid >> 1;
    const int a_col = (tid & 1) * 16;
    const int b_n = (tid & 31) * 4;
    const int b_k = (tid >> 5) * 4;
    for (int k0 = 0; k0 < K; k0 += 32) {
        __syncthreads();
        {
            const AT* src = A + (size_t)(row0 + a_row) * K + k0 + a_col;
            if constexpr (sizeof(AT) == 4) {
                const float* sf = reinterpret_cast<const float*>(src);
                f32x4 v0 = *(const f32x4*)(sf + 0);
                f32x4 v1 = *(const f32x4*)(sf + 4);
                f32x4 v2 = *(const f32x4*)(sf + 8);
                f32x4 v3 = *(const f32x4*)(sf + 12);
                bf16x8 w0, w1;
                w0[0] = f2bf(v0[0]); w0[1] = f2bf(v0[1]); w0[2] = f2bf(v0[2]); w0[3] = f2bf(v0[3]);
                w0[4] = f2bf(v1[0]); w0[5] = f2bf(v1[1]); w0[6] = f2bf(v1[2]); w0[7] = f2bf(v1[3]);
                w1[0] = f2bf(v2[0]); w1[1] = f2bf(v2[1]); w1[2] = f2bf(v2[2]); w1[3] = f2bf(v2[3]);
                w1[4] = f2bf(v3[0]); w1[5] = f2bf(v3[1]); w1[6] = f2bf(v3[2]); w1[7] = f2bf(v3[3]);
                *(bf16x8*)&As[a_row][a_col + 0] = w0;
                *(bf16x8*)&As[a_row][a_col + 8] = w1;
            } else {
                const short* ss = reinterpret_cast<const short*>(src);
                *(bf16x8*)&As[a_row][a_col + 0] = *(const bf16x8*)(ss + 0);
                *(bf16x8*)&As[a_row][a_col + 8] = *(const bf16x8*)(ss + 8);
            }
        }
        {
            const float* w0p = W + (size_t)(k0 + b_k + 0) * N + col0 + b_n;
            f32x4 r0 = *(const f32x4*)(w0p);
            f32x4 r1 = *(const f32x4*)(w0p + N);
            f32x4 r2 = *(const f32x4*)(w0p + 2 * N);
            f32x4 r3 = *(const f32x4*)(w0p + 3 * N);
#pragma unroll
            for (int j = 0; j < 4; j++) {
                bf16x4 t;
                t[0] = f2bf(r0[j]); t[1] = f2bf(r1[j]); t[2] = f2bf(r2[j]); t[3] = f2bf(r3[j]);
                *(bf16x4*)&Bs[b_n + j][b_k] = t;
            }
        }
        __syncthreads();
        bf16x8 af[4], bfr[4];
#pragma unroll
        for (int m = 0; m < 4; m++)
            af[m] = *(const bf16x8*)&As[wm * 64 + m * 16 + (lane & 15)][(lane >> 4) * 8];
#pragma unroll
        for (int n = 0; n < 4; n++)
            bfr[n] = *(const bf16x8*)&Bs[wn * 64 + n * 16 + (lane & 15)][(lane >> 4) * 8];
#pragma unroll
        for (int m = 0; m < 4; m++)
#pragma unroll
            for (int n = 0; n < 4; n++)
                acc[m][n] = MFMA16(af[m], bfr[n], acc[m][n]);
    }
#pragma unroll
    for (int m = 0; m < 4; m++) {
#pragma unroll
        for (int n = 0; n < 4; n++) {
            const int col = col0 + wn * 64 + n * 16 + (lane & 15);
            const float bz = bias[col];
#pragma unroll
            for (int j = 0; j < 4; j++) {
                const int row = row0 + wm * 64 + m * 16 + (lane >> 4) * 4 + j;
                const float v = (acc[m][n][j] + bz) * oscale;
                if constexpr (sizeof(OT) == 2)
                    C[(size_t)row * N + col] = (OT)f2bf(v);
                else
                    C[(size_t)row * N + col] = (OT)v;
            }
        }
    }
}

// ---------------------------------------------------------------------------
// Flash attention v9 (unchanged): 8 waves, QBLK=256, KVBLK=128, in-register
// softmax, conflict-free swizzle, K/V^T via global_load_lds, kg-pipelined.
// ---------------------------------------------------------------------------
__global__ __launch_bounds__(512, 2) void attn_kernel(
    const short* __restrict__ Qp, const short* __restrict__ Kp,
    const short* __restrict__ Vtp, short* __restrict__ Oout) {
    const int nwg = gridDim.x;
    const int bid = blockIdx.x;
    const int bx = (bid & 7) * (nwg >> 3) + (bid >> 3);
    const int qt = bx & 7;            // SEQ/256 = 8
    const int h = (bx >> 3) & 15;
    const int b = bx >> 7;

    __shared__ short Ks[2][128 * 128];   // [key][d], 256B rows, XOR (key&15)<<4
    __shared__ short Vts[2][128 * 128];  // [d][key], 256B rows, XOR (d&15)<<4

    const int tid = threadIdx.x;
    const int lane = tid & 63;
    const int wid = tid >> 6;           // 0..7
    const int lo = lane & 31;
    const int hi1 = lane >> 5;

    bf16x8 qf[8];
    {
        const short* qrow = Qp + (size_t)(b * SEQ + qt * 256 + wid * 32 + lo) * DMODEL + h * DK;
#pragma unroll
        for (int dk = 0; dk < 8; dk++)
            qf[dk] = *(const bf16x8*)(qrow + dk * 16 + hi1 * 8);
    }

    f32x16 oacc[4] = {};
    float lsum = 0.f;

    const char* Kbase = (const char*)(Kp + (size_t)(b * SEQ) * DMODEL + h * DK);
    const char* Vtbase = (const char*)(Vtp + (size_t)(h * DK) * MROWS + b * SEQ);

    const int srow = wid * 16 + (lane >> 4);
    const int scp = (lane & 15) * 16;
    const int NT = SEQ / 128;                   // 16
    const float C12 = 17.3123404906676f;        // 12 * log2(e)

#pragma unroll
    for (int i = 0; i < 4; i++) {
        const int rr = srow + i * 4;
        load_lds16(Kbase + (size_t)rr * (DMODEL * 2) + (scp ^ ((rr & 15) << 4)),
                   (char*)Ks[0] + wid * 4096 + i * 1024);
    }
#pragma unroll
    for (int i = 0; i < 4; i++) {
        const int dd = srow + i * 4;
        load_lds16(Vtbase + (size_t)dd * (MROWS * 2) + (scp ^ ((dd & 15) << 4)),
                   (char*)Vts[0] + wid * 4096 + i * 1024);
    }
    asm volatile("s_waitcnt vmcnt(0)" ::: "memory");
    __builtin_amdgcn_s_barrier();
    __builtin_amdgcn_sched_barrier(0);

    for (int kt = 0; kt < NT; kt++) {
        const int cur = kt & 1;
        const bool more = (kt + 1) < NT;

        if (more) {
#pragma unroll
            for (int i = 0; i < 4; i++) {
                const int rr = srow + i * 4;
                load_lds16(Kbase + (size_t)((kt + 1) * 128 + rr) * (DMODEL * 2) + (scp ^ ((rr & 15) << 4)),
                           (char*)Ks[cur ^ 1] + wid * 4096 + i * 1024);
            }
#pragma unroll
            for (int i = 0; i < 4; i++) {
                const int dd = srow + i * 4;
                load_lds16(Vtbase + (size_t)dd * (MROWS * 2) + (kt + 1) * 256 + (scp ^ ((dd & 15) << 4)),
                           (char*)Vts[cur ^ 1] + wid * 4096 + i * 1024);
            }
        }

        f32x16 sc[2];
        bf16x8 pa[8];

        sc[0] = (f32x16){};
        __builtin_amdgcn_s_setprio(1);
#pragma unroll
        for (int dk = 0; dk < 8; dk++) {
            const int r = 0 * 32 + lo;
            const int cb = (dk * 32 + hi1 * 16) ^ ((r & 15) << 4);
            bf16x8 kf = *(const bf16x8*)((char*)Ks[cur] + r * 256 + cb);
            sc[0] = MFMA32(kf, qf[dk], sc[0]);
        }
        __builtin_amdgcn_s_setprio(0);

#pragma unroll
        for (int g = 0; g < 4; g++) {
            if (g < 3) {
                sc[(g + 1) & 1] = (f32x16){};
                __builtin_amdgcn_s_setprio(1);
#pragma unroll
                for (int dk = 0; dk < 8; dk++) {
                    const int r = (g + 1) * 32 + lo;
                    const int cb = (dk * 32 + hi1 * 16) ^ ((r & 15) << 4);
                    bf16x8 kf = *(const bf16x8*)((char*)Ks[cur] + r * 256 + cb);
                    sc[(g + 1) & 1] = MFMA32(kf, qf[dk], sc[(g + 1) & 1]);
                }
                __builtin_amdgcn_s_setprio(0);
            }
            {
                f32x16& s = sc[g & 1];
#pragma unroll
                for (int r = 0; r < 16; r++)
                    s[r] = exp2_fast(s[r] - C12);
                float s0 = 0.f, s1 = 0.f, s2 = 0.f, s3 = 0.f;
#pragma unroll
                for (int r = 0; r < 16; r += 4) {
                    s0 += s[r]; s1 += s[r + 1]; s2 += s[r + 2]; s3 += s[r + 3];
                }
                lsum += (s0 + s1) + (s2 + s3);
#pragma unroll
                for (int hf = 0; hf < 2; hf++) {
                    const int X0 = cvt_pk_bf16(s[8 * hf + 0], s[8 * hf + 1]);
                    const int X1 = cvt_pk_bf16(s[8 * hf + 2], s[8 * hf + 3]);
                    const int X2 = cvt_pk_bf16(s[8 * hf + 4], s[8 * hf + 5]);
                    const int X3 = cvt_pk_bf16(s[8 * hf + 6], s[8 * hf + 7]);
                    const int L0 = hi1 ? X2 : X0, L1 = hi1 ? X3 : X1;
                    const int S0 = hi1 ? X0 : X2, S1 = hi1 ? X1 : X3;
                    const int R0 = __shfl_xor(S0, 32, 64);
                    const int R1 = __shfl_xor(S1, 32, 64);
                    union { int i[4]; bf16x8 v; } u;
                    u.i[0] = hi1 ? R0 : L0;
                    u.i[1] = hi1 ? R1 : L1;
                    u.i[2] = hi1 ? L0 : R0;
                    u.i[3] = hi1 ? L1 : R1;
                    pa[2 * g + hf] = u.v;
                }
            }
        }

        __builtin_amdgcn_s_setprio(1);
#pragma unroll
        for (int ks = 0; ks < 8; ks++) {
#pragma unroll
            for (int n = 0; n < 4; n++) {
                const int d = n * 32 + lo;
                const int cb = (ks * 32 + hi1 * 16) ^ ((d & 15) << 4);
                bf16x8 vf = *(const bf16x8*)((char*)Vts[cur] + d * 256 + cb);
                oacc[n] = MFMA32(vf, pa[ks], oacc[n]);
            }
        }
        __builtin_amdgcn_s_setprio(0);

        if (more) {
            asm volatile("s_waitcnt vmcnt(0)" ::: "memory");
            asm volatile("s_waitcnt lgkmcnt(0)" ::: "memory");
            __builtin_amdgcn_s_barrier();
            __builtin_amdgcn_sched_barrier(0);
        }
    }

    const float l = lsum + __shfl_xor(lsum, 32, 64);
    const float inv = 1.0f / l;
    short* obase = Oout + (size_t)(b * SEQ + qt * 256 + wid * 32 + lo) * DMODEL + h * DK;
#pragma unroll
    for (int n = 0; n < 4; n++) {
#pragma unroll
        for (int rr = 0; rr < 8; rr++) {
            const int d = n * 32 + 2 * (rr & 1) + 8 * (rr >> 1) + 4 * hi1;
            const int pkv = cvt_pk_bf16(oacc[n][2 * rr] * inv, oacc[n][2 * rr + 1] * inv);
            *(int*)(obase + d) = pkv;
        }
    }
}

// ---------------------------------------------------------------------------
extern "C" void kernel_launch(void* const* d_in, const int* in_sizes, int n_in,
                              void* d_out, int out_size, void* d_ws, size_t ws_size,
                              hipStream_t stream) {
    const float* q   = (const float*)d_in[0];
    const float* k   = (const float*)d_in[1];
    const float* v   = (const float*)d_in[2];
    const float* w_q = (const float*)d_in[3];
    const float* b_q = (const float*)d_in[4];
    const float* w_k = (const float*)d_in[5];
    const float* b_k = (const float*)d_in[6];
    const float* w_v = (const float*)d_in[7];
    const float* b_v = (const float*)d_in[8];
    const float* w_o = (const float*)d_in[9];
    const float* b_o = (const float*)d_in[10];
    float* out = (float*)d_out;

    const size_t PROJ = (size_t)MROWS * DMODEL;
    const size_t WSZ = (size_t)DMODEL * DMODEL;
    // 1/sqrt(128) * log2(e): exp2-based softmax
    const float qscale = 0.08838834764831845f * 1.4426950408889634f;
    const int attn_grid = BATCH * HEADS * (SEQ / 256);  // 512

    if (ws_size >= (6 * PROJ + 4 * WSZ) * sizeof(short)) {
        short* qbf = (short*)d_ws;
        short* kbf = qbf + PROJ;
        short* vbf = kbf + PROJ;
        short* Qp  = vbf + PROJ;
        short* Kp  = Qp + PROJ;
        short* Vt  = Kp + PROJ;   // V^T [DMODEL][MROWS]
        short* wtq = Vt + PROJ;
        short* wtk = wtq + WSZ;
        short* wtv = wtk + WSZ;
        short* wto = wtv + WSZ;
        short* Ao  = qbf;  // reuse (qbf dead after Q projection)

        const int n8 = (int)(PROJ / 8);
        cvt3_bf16<<<3072, 256, 0, stream>>>(q, k, v, qbf, kbf, vbf, n8);
        dim3 gtr(DMODEL / 64, DMODEL / 64, 4);
        cvt_tr4<<<gtr, 256, 0, stream>>>(w_q, w_k, w_v, w_o, wtq, wtk, wtv, wto);

        // fused QKV projections: 768 blocks -> 2 resident blocks/CU
        gemm8_qkv<<<768, 512, 0, stream>>>(qbf, kbf, vbf, wtq, wtk, wtv,
                                           b_q, b_k, b_v, Qp, Kp, Vt, qscale);

        attn_kernel<<<attn_grid, 512, 0, stream>>>(Qp, Kp, Vt, Ao);

        gemm8_one<float><<<256, 512, 0, stream>>>(Ao, wto, b_o, out, 1.0f);
    } else {
        // fallback: 5 x PROJ layout (Qp,Kp,Vp,Vt,Ao)
        short* Qp = (short*)d_ws;
        short* Kp = Qp + PROJ;
        short* Vp = Kp + PROJ;
        short* Vt = Vp + PROJ;
        short* Ao = Vt + PROJ;
        dim3 gblk(DMODEL / 128, MROWS / 128);
        gemm_kernel<float, short><<<gblk, 256, 0, stream>>>(q, w_q, b_q, Qp, qscale);
        gemm_kernel<float, short><<<gblk, 256, 0, stream>>>(k, w_k, b_k, Kp, 1.0f);
        gemm_kernel<float, short><<<gblk, 256, 0, stream>>>(v, w_v, b_v, Vp, 1.0f);
        dim3 gtrv(DMODEL / 64, MROWS / 64);
        tr_bf16<<<gtrv, 256, 0, stream>>>(Vp, Vt);
        attn_kernel<<<attn_grid, 512, 0, stream>>>(Qp, Kp, Vt, Ao);
        gemm_kernel<short, float><<<gblk, 256, 0, stream>>>(Ao, w_o, b_o, out, 1.0f);
    }
}

// Round 14
// 525.149 us; speedup vs baseline: 1.0940x; 1.0208x over previous
//
#include <hip/hip_runtime.h>
#include <hip/hip_bf16.h>

#define DMODEL 2048
#define HEADS 16
#define DK 128
#define BATCH 4
#define SEQ 2048
#define MROWS (BATCH * SEQ)  // 8192

typedef __attribute__((ext_vector_type(8))) short bf16x8;
typedef __attribute__((ext_vector_type(4))) short bf16x4;
typedef __attribute__((ext_vector_type(4))) float f32x4;
typedef __attribute__((ext_vector_type(2))) float f32x2;
typedef __attribute__((ext_vector_type(16))) float f32x16;

static __device__ __forceinline__ short f2bf(float x) {
    __hip_bfloat16 h = __float2bfloat16(x);
    union { __hip_bfloat16 h; short s; } u;
    u.h = h;
    return u.s;
}

static __device__ __forceinline__ int cvt_pk_bf16(float lo, float hi) {
    int r;
    asm("v_cvt_pk_bf16_f32 %0, %1, %2" : "=v"(r) : "v"(lo), "v"(hi));
    return r;
}

static __device__ __forceinline__ float exp2_fast(float x) {
    float r;
    asm("v_exp_f32 %0, %1" : "=v"(r) : "v"(x));
    return r;
}

#define MFMA16(a, b, c) __builtin_amdgcn_mfma_f32_16x16x32_bf16((a), (b), (c), 0, 0, 0)
#define MFMA32(a, b, c) __builtin_amdgcn_mfma_f32_32x32x16_bf16((a), (b), (c), 0, 0, 0)

static __device__ __forceinline__ void load_lds16(const void* g, void* l) {
    __builtin_amdgcn_global_load_lds(
        (const __attribute__((address_space(1))) unsigned int*)g,
        (__attribute__((address_space(3))) unsigned int*)l, 16, 0, 0);
}

// ---------------------------------------------------------------------------
// Fused converts (one dispatch): z in 0..2 -> fp32->bf16 elementwise (q,k,v);
// z in 3..6 -> fp32 [K][N] -> bf16 [N][K] weight transpose (wq,wk,wv,wo).
// ---------------------------------------------------------------------------
__global__ __launch_bounds__(256) void cvt_all(
    const float* __restrict__ i0, const float* __restrict__ i1,
    const float* __restrict__ i2, short* __restrict__ o0,
    short* __restrict__ o1, short* __restrict__ o2,
    const float* __restrict__ w0, const float* __restrict__ w1,
    const float* __restrict__ w2, const float* __restrict__ w3,
    short* __restrict__ t0, short* __restrict__ t1,
    short* __restrict__ t2, short* __restrict__ t3, int n8) {
    const int z = blockIdx.z;
    const int tid = threadIdx.x;
    if (z < 3) {
        const float* in = z == 0 ? i0 : (z == 1 ? i1 : i2);
        short* out = z == 0 ? o0 : (z == 1 ? o1 : o2);
        const int lb = blockIdx.y * 32 + blockIdx.x;  // 0..1023
        int i = lb * 256 + tid;
        const int stride = 1024 * 256;
        for (; i < n8; i += stride) {
            f32x4 a = ((const f32x4*)in)[i * 2];
            f32x4 b = ((const f32x4*)in)[i * 2 + 1];
            bf16x8 o;
            o[0] = f2bf(a[0]); o[1] = f2bf(a[1]); o[2] = f2bf(a[2]); o[3] = f2bf(a[3]);
            o[4] = f2bf(b[0]); o[5] = f2bf(b[1]); o[6] = f2bf(b[2]); o[7] = f2bf(b[3]);
            ((bf16x8*)out)[i] = o;
        }
    } else {
        __shared__ short t[64][72];
        const int which = z - 3;
        const float* W = which == 0 ? w0 : (which == 1 ? w1 : (which == 2 ? w2 : w3));
        short* Wt = which == 0 ? t0 : (which == 1 ? t1 : (which == 2 ? t2 : t3));
        const int n0 = blockIdx.x * 64, k0 = blockIdx.y * 64;
#pragma unroll
        for (int p = 0; p < 4; p++) {
            const int kr = p * 16 + (tid >> 4);
            const int nc = (tid & 15) * 4;
            f32x4 v = *(const f32x4*)&W[(size_t)(k0 + kr) * DMODEL + n0 + nc];
#pragma unroll
            for (int j = 0; j < 4; j++) t[nc + j][kr] = f2bf(v[j]);
        }
        __syncthreads();
        const int nr = tid >> 2, ch = (tid & 3) * 16;
        *(bf16x8*)&Wt[(size_t)(n0 + nr) * DMODEL + k0 + ch] = *(const bf16x8*)&t[nr][ch];
        *(bf16x8*)&Wt[(size_t)(n0 + nr) * DMODEL + k0 + ch + 8] = *(const bf16x8*)&t[nr][ch + 8];
    }
}

// ---------------------------------------------------------------------------
// bf16 [MROWS][DMODEL] -> bf16 [DMODEL][MROWS] transpose (fallback path only)
// ---------------------------------------------------------------------------
__global__ __launch_bounds__(256) void tr_bf16(const short* __restrict__ in,
                                               short* __restrict__ out) {
    __shared__ short t[64][65];
    const int c0 = blockIdx.x * 64, r0 = blockIdx.y * 64;
    const int tid = threadIdx.x;
    const int row = tid >> 2, cb = (tid & 3) * 16;
    bf16x8 a = *(const bf16x8*)&in[(size_t)(r0 + row) * DMODEL + c0 + cb];
    bf16x8 b2 = *(const bf16x8*)&in[(size_t)(r0 + row) * DMODEL + c0 + cb + 8];
#pragma unroll
    for (int j = 0; j < 8; j++) { t[cb + j][row] = a[j]; t[cb + 8 + j][row] = b2[j]; }
    __syncthreads();
#pragma unroll
    for (int j = 0; j < 16; j++)
        out[(size_t)(c0 + row) * MROWS + r0 + cb + j] = t[row][cb + j];
}

// ---------------------------------------------------------------------------
// gemm8 core (verified 4-phase 256x256 schedule): BK=64, 8 waves (2Mx4N),
// single 64KB LDS buffer, counted vmcnt, region-rotated staging.
// Epilogue uses lane-pair exchange (shfl_xor 1) to emit packed 4B (bf16 pair)
// or 8B (float2) stores instead of scalar 2B/4B — halves store instructions
// and removes partial-line write amplification.
// ---------------------------------------------------------------------------
static __device__ __forceinline__ void stage2(const char* gbase, char* lbase,
                                              int rb, int r8, int scol, int ktb) {
#pragma unroll
    for (int i = 0; i < 2; i++)
        load_lds16(gbase + (size_t)(rb + i * 8 + r8) * (DMODEL * 2) + ktb + scol,
                   lbase + (rb + i * 8) * 128);
}

template <typename OT>
static __device__ __forceinline__ void gemm8_impl(
    char* Asl, char* Bsl,
    const short* __restrict__ A, const short* __restrict__ Bt,
    const float* __restrict__ bias, OT* __restrict__ C,
    float oscale, bool transv, int bx, int by) {
    const int tid = threadIdx.x, lane = tid & 63, wid = tid >> 6;
    const int row0 = by * 256, col0 = bx * 256;
    const int wm = wid >> 2, wn = wid & 3;

    const int r8 = lane >> 3;
    const int scol = ((lane & 7) * 16) ^ (r8 << 4);
    const int a1r = ((wid & 4) << 5) + (wid & 3) * 16;
    const int b1r = (wid >> 1) * 64 + (wid & 1) * 16;

    const char* Ab = (const char*)A + (size_t)row0 * (DMODEL * 2);
    const char* Bb = (const char*)Bt + (size_t)col0 * (DMODEL * 2);

    const int arow = wm * 128 + (lane & 15);
    const int brow = wn * 64 + (lane & 15);
    const int fg = (lane >> 4) * 16;
    const int fx = (lane & 7) << 4;

    f32x4 acc[8][4] = {};
    bf16x8 af[4][2], bfr[4][2];

    const int NT = DMODEL / 64;

    stage2(Ab, Asl, a1r, r8, scol, 0);
    stage2(Bb, Bsl, b1r, r8, scol, 0);
    stage2(Bb, Bsl, b1r + 32, r8, scol, 0);
    stage2(Ab, Asl, a1r + 64, r8, scol, 0);

    for (int t = 0; t < NT; t++) {
        const bool more = (t + 1) < NT;
        const int ktb = (t + 1) * 128;

        // phase 0
        asm volatile("s_waitcnt vmcnt(4)" ::: "memory");
        asm volatile("s_waitcnt lgkmcnt(0)" ::: "memory");
        __builtin_amdgcn_s_barrier();
        __builtin_amdgcn_sched_barrier(0);
#pragma unroll
        for (int m = 0; m < 4; m++)
#pragma unroll
            for (int kk = 0; kk < 2; kk++)
                af[m][kk] = *(const bf16x8*)(Asl + (arow + m * 16) * 128 + ((kk * 64 + fg) ^ fx));
#pragma unroll
        for (int n = 0; n < 2; n++)
#pragma unroll
            for (int kk = 0; kk < 2; kk++)
                bfr[n][kk] = *(const bf16x8*)(Bsl + (brow + n * 16) * 128 + ((kk * 64 + fg) ^ fx));
        __builtin_amdgcn_s_setprio(1);
#pragma unroll
        for (int m = 0; m < 4; m++)
#pragma unroll
            for (int n = 0; n < 2; n++)
#pragma unroll
                for (int kk = 0; kk < 2; kk++)
                    acc[m][n] = MFMA16(af[m][kk], bfr[n][kk], acc[m][n]);
        __builtin_amdgcn_s_setprio(0);

        // phase 1
        asm volatile("s_waitcnt vmcnt(2)" ::: "memory");
        asm volatile("s_waitcnt lgkmcnt(0)" ::: "memory");
        __builtin_amdgcn_s_barrier();
        __builtin_amdgcn_sched_barrier(0);
#pragma unroll
        for (int n = 2; n < 4; n++)
#pragma unroll
            for (int kk = 0; kk < 2; kk++)
                bfr[n][kk] = *(const bf16x8*)(Bsl + (brow + n * 16) * 128 + ((kk * 64 + fg) ^ fx));
        if (more) {
            stage2(Ab, Asl, a1r, r8, scol, ktb);
            stage2(Bb, Bsl, b1r, r8, scol, ktb);
        }
        __builtin_amdgcn_s_setprio(1);
#pragma unroll
        for (int m = 0; m < 4; m++)
#pragma unroll
            for (int n = 2; n < 4; n++)
#pragma unroll
                for (int kk = 0; kk < 2; kk++)
                    acc[m][n] = MFMA16(af[m][kk], bfr[n][kk], acc[m][n]);
        __builtin_amdgcn_s_setprio(0);

        // phase 2
        if (more) asm volatile("s_waitcnt vmcnt(4)" ::: "memory");
        else      asm volatile("s_waitcnt vmcnt(0)" ::: "memory");
        asm volatile("s_waitcnt lgkmcnt(0)" ::: "memory");
        __builtin_amdgcn_s_barrier();
        __builtin_amdgcn_sched_barrier(0);
#pragma unroll
        for (int mi = 0; mi < 4; mi++)
#pragma unroll
            for (int kk = 0; kk < 2; kk++)
                af[mi][kk] = *(const bf16x8*)(Asl + (arow + 64 + mi * 16) * 128 + ((kk * 64 + fg) ^ fx));
        if (more) stage2(Bb, Bsl, b1r + 32, r8, scol, ktb);
        __builtin_amdgcn_s_setprio(1);
#pragma unroll
        for (int mi = 0; mi < 4; mi++)
#pragma unroll
            for (int n = 2; n < 4; n++)
#pragma unroll
                for (int kk = 0; kk < 2; kk++)
                    acc[4 + mi][n] = MFMA16(af[mi][kk], bfr[n][kk], acc[4 + mi][n]);
        __builtin_amdgcn_s_setprio(0);

        // phase 3
        asm volatile("s_waitcnt lgkmcnt(0)" ::: "memory");
        __builtin_amdgcn_s_barrier();
        __builtin_amdgcn_sched_barrier(0);
        if (more) stage2(Ab, Asl, a1r + 64, r8, scol, ktb);
        __builtin_amdgcn_s_setprio(1);
#pragma unroll
        for (int mi = 0; mi < 4; mi++)
#pragma unroll
            for (int n = 0; n < 2; n++)
#pragma unroll
                for (int kk = 0; kk < 2; kk++)
                    acc[4 + mi][n] = MFMA16(af[mi][kk], bfr[n][kk], acc[4 + mi][n]);
        __builtin_amdgcn_s_setprio(0);
    }

    // ---- epilogue ----
    const int l15 = lane & 15;
    const int odd = l15 & 1;
#pragma unroll
    for (int n = 0; n < 4; n++) {
        const int col = col0 + wn * 64 + n * 16 + l15;
        const float bz = bias[col];
#pragma unroll
        for (int m = 0; m < 8; m++) {
            const int row4 = row0 + wm * 128 + m * 16 + (lane >> 4) * 4;
            if (transv) {
                bf16x4 tv;
#pragma unroll
                for (int j = 0; j < 4; j++) tv[j] = f2bf((acc[m][n][j] + bz) * oscale);
                *(bf16x4*)&((short*)C)[(size_t)col * MROWS + row4] = tv;
            } else {
                // lane-pair exchange: even lane emits rows {0,1}, odd rows {2,3},
                // each covering cols {c, c+1} (c = col & ~1) as packed stores.
                float w0 = (acc[m][n][0] + bz) * oscale;
                float w1 = (acc[m][n][1] + bz) * oscale;
                float w2 = (acc[m][n][2] + bz) * oscale;
                float w3 = (acc[m][n][3] + bz) * oscale;
                const float p0 = __shfl_xor(w0, 1, 64);
                const float p1 = __shfl_xor(w1, 1, 64);
                const float p2 = __shfl_xor(w2, 1, 64);
                const float p3 = __shfl_xor(w3, 1, 64);
                const int ceven = col - odd;
                const int rbase = row4 + (odd ? 2 : 0);
                const float aL = odd ? p2 : w0, aH = odd ? w2 : p0;
                const float bL = odd ? p3 : w1, bH = odd ? w3 : p1;
                if constexpr (sizeof(OT) == 2) {
                    *(int*)&C[(size_t)rbase * DMODEL + ceven] = cvt_pk_bf16(aL, aH);
                    *(int*)&C[(size_t)(rbase + 1) * DMODEL + ceven] = cvt_pk_bf16(bL, bH);
                } else {
                    f32x2 u0, u1;
                    u0[0] = aL; u0[1] = aH;
                    u1[0] = bL; u1[1] = bH;
                    *(f32x2*)&C[(size_t)rbase * DMODEL + ceven] = u0;
                    *(f32x2*)&C[(size_t)(rbase + 1) * DMODEL + ceven] = u1;
                }
            }
        }
    }
}

// single-GEMM launcher (O projection): grid 256
template <typename OT>
__global__ __launch_bounds__(512, 2) void gemm8_one(
    const short* __restrict__ A, const short* __restrict__ Bt,
    const float* __restrict__ bias, OT* __restrict__ C, float oscale) {
    __shared__ short Asl[256 * 64];
    __shared__ short Bsl[256 * 64];
    const int nwg = gridDim.x;
    const int bid = blockIdx.x;
    const int swz = (bid & 7) * (nwg >> 3) + (bid >> 3);
    const int bx = swz >> 5, by = swz & 31;
    gemm8_impl<OT>((char*)Asl, (char*)Bsl, A, Bt, bias, C, oscale, false, bx, by);
}

// fused QKV launcher: grid 768 = 3 x 256 (tensor-major block order)
__global__ __launch_bounds__(512, 2) void gemm8_qkv(
    const short* __restrict__ qA, const short* __restrict__ kA,
    const short* __restrict__ vA, const short* __restrict__ wq,
    const short* __restrict__ wk, const short* __restrict__ wv,
    const float* __restrict__ bq, const float* __restrict__ bk,
    const float* __restrict__ bv, short* __restrict__ Qp,
    short* __restrict__ Kp, short* __restrict__ Vt, float qscale) {
    __shared__ short Asl[256 * 64];
    __shared__ short Bsl[256 * 64];
    const int bid = blockIdx.x;
    const int which = bid >> 8;       // 0=q 1=k 2=v
    const int lb = bid & 255;
    const int swz = (lb & 7) * 32 + (lb >> 3);
    const int bx = swz >> 5, by = swz & 31;
    const short* A = which == 0 ? qA : (which == 1 ? kA : vA);
    const short* Bt = which == 0 ? wq : (which == 1 ? wk : wv);
    const float* bias = which == 0 ? bq : (which == 1 ? bk : bv);
    short* C = which == 0 ? Qp : (which == 1 ? Kp : Vt);
    const float os = which == 0 ? qscale : 1.0f;
    gemm8_impl<short>((char*)Asl, (char*)Bsl, A, Bt, bias, C, os, which == 2, bx, by);
}

// ---------------------------------------------------------------------------
// Fallback GEMM (round-0): A fp32 or bf16, conversion in staging.
// ---------------------------------------------------------------------------
template <typename AT, typename OT>
__global__ __launch_bounds__(256) void gemm_kernel(
    const AT* __restrict__ A, const float* __restrict__ W,
    const float* __restrict__ bias, OT* __restrict__ C, float oscale) {
    const int K = DMODEL, N = DMODEL;
    __shared__ short As[128][40];
    __shared__ short Bs[128][40];
    const int tid = threadIdx.x;
    const int lane = tid & 63;
    const int wid = tid >> 6;
    const int wm = wid >> 1, wn = wid & 1;
    const int row0 = blockIdx.y * 128;
    const int col0 = blockIdx.x * 128;
    f32x4 acc[4][4] = {};
    const int a_row = tid >> 1;
    const int a_col = (tid & 1) * 16;
    const int b_n = (tid & 31) * 4;
    const int b_k = (tid >> 5) * 4;
    for (int k0 = 0; k0 < K; k0 += 32) {
        __syncthreads();
        {
            const AT* src = A + (size_t)(row0 + a_row) * K + k0 + a_col;
            if constexpr (sizeof(AT) == 4) {
                const float* sf = reinterpret_cast<const float*>(src);
                f32x4 v0 = *(const f32x4*)(sf + 0);
                f32x4 v1 = *(const f32x4*)(sf + 4);
                f32x4 v2 = *(const f32x4*)(sf + 8);
                f32x4 v3 = *(const f32x4*)(sf + 12);
                bf16x8 w0, w1;
                w0[0] = f2bf(v0[0]); w0[1] = f2bf(v0[1]); w0[2] = f2bf(v0[2]); w0[3] = f2bf(v0[3]);
                w0[4] = f2bf(v1[0]); w0[5] = f2bf(v1[1]); w0[6] = f2bf(v1[2]); w0[7] = f2bf(v1[3]);
                w1[0] = f2bf(v2[0]); w1[1] = f2bf(v2[1]); w1[2] = f2bf(v2[2]); w1[3] = f2bf(v2[3]);
                w1[4] = f2bf(v3[0]); w1[5] = f2bf(v3[1]); w1[6] = f2bf(v3[2]); w1[7] = f2bf(v3[3]);
                *(bf16x8*)&As[a_row][a_col + 0] = w0;
                *(bf16x8*)&As[a_row][a_col + 8] = w1;
            } else {
                const short* ss = reinterpret_cast<const short*>(src);
                *(bf16x8*)&As[a_row][a_col + 0] = *(const bf16x8*)(ss + 0);
                *(bf16x8*)&As[a_row][a_col + 8] = *(const bf16x8*)(ss + 8);
            }
        }
        {
            const float* w0p = W + (size_t)(k0 + b_k + 0) * N + col0 + b_n;
            f32x4 r0 = *(const f32x4*)(w0p);
            f32x4 r1 = *(const f32x4*)(w0p + N);
            f32x4 r2 = *(const f32x4*)(w0p + 2 * N);
            f32x4 r3 = *(const f32x4*)(w0p + 3 * N);
#pragma unroll
            for (int j = 0; j < 4; j++) {
                bf16x4 t;
                t[0] = f2bf(r0[j]); t[1] = f2bf(r1[j]); t[2] = f2bf(r2[j]); t[3] = f2bf(r3[j]);
                *(bf16x4*)&Bs[b_n + j][b_k] = t;
            }
        }
        __syncthreads();
        bf16x8 af[4], bfr[4];
#pragma unroll
        for (int m = 0; m < 4; m++)
            af[m] = *(const bf16x8*)&As[wm * 64 + m * 16 + (lane & 15)][(lane >> 4) * 8];
#pragma unroll
        for (int n = 0; n < 4; n++)
            bfr[n] = *(const bf16x8*)&Bs[wn * 64 + n * 16 + (lane & 15)][(lane >> 4) * 8];
#pragma unroll
        for (int m = 0; m < 4; m++)
#pragma unroll
            for (int n = 0; n < 4; n++)
                acc[m][n] = MFMA16(af[m], bfr[n], acc[m][n]);
    }
#pragma unroll
    for (int m = 0; m < 4; m++) {
#pragma unroll
        for (int n = 0; n < 4; n++) {
            const int col = col0 + wn * 64 + n * 16 + (lane & 15);
            const float bz = bias[col];
#pragma unroll
            for (int j = 0; j < 4; j++) {
                const int row = row0 + wm * 64 + m * 16 + (lane >> 4) * 4 + j;
                const float v = (acc[m][n][j] + bz) * oscale;
                if constexpr (sizeof(OT) == 2)
                    C[(size_t)row * N + col] = (OT)f2bf(v);
                else
                    C[(size_t)row * N + col] = (OT)v;
            }
        }
    }
}

// ---------------------------------------------------------------------------
// Flash attention v9 (unchanged): 8 waves, QBLK=256, KVBLK=128, in-register
// softmax, conflict-free swizzle, K/V^T via global_load_lds, kg-pipelined.
// ---------------------------------------------------------------------------
__global__ __launch_bounds__(512, 2) void attn_kernel(
    const short* __restrict__ Qp, const short* __restrict__ Kp,
    const short* __restrict__ Vtp, short* __restrict__ Oout) {
    const int nwg = gridDim.x;
    const int bid = blockIdx.x;
    const int bx = (bid & 7) * (nwg >> 3) + (bid >> 3);
    const int qt = bx & 7;            // SEQ/256 = 8
    const int h = (bx >> 3) & 15;
    const int b = bx >> 7;

    __shared__ short Ks[2][128 * 128];   // [key][d], 256B rows, XOR (key&15)<<4
    __shared__ short Vts[2][128 * 128];  // [d][key], 256B rows, XOR (d&15)<<4

    const int tid = threadIdx.x;
    const int lane = tid & 63;
    const int wid = tid >> 6;           // 0..7
    const int lo = lane & 31;
    const int hi1 = lane >> 5;

    bf16x8 qf[8];
    {
        const short* qrow = Qp + (size_t)(b * SEQ + qt * 256 + wid * 32 + lo) * DMODEL + h * DK;
#pragma unroll
        for (int dk = 0; dk < 8; dk++)
            qf[dk] = *(const bf16x8*)(qrow + dk * 16 + hi1 * 8);
    }

    f32x16 oacc[4] = {};
    float lsum = 0.f;

    const char* Kbase = (const char*)(Kp + (size_t)(b * SEQ) * DMODEL + h * DK);
    const char* Vtbase = (const char*)(Vtp + (size_t)(h * DK) * MROWS + b * SEQ);

    const int srow = wid * 16 + (lane >> 4);
    const int scp = (lane & 15) * 16;
    const int NT = SEQ / 128;                   // 16
    const float C12 = 17.3123404906676f;        // 12 * log2(e)

#pragma unroll
    for (int i = 0; i < 4; i++) {
        const int rr = srow + i * 4;
        load_lds16(Kbase + (size_t)rr * (DMODEL * 2) + (scp ^ ((rr & 15) << 4)),
                   (char*)Ks[0] + wid * 4096 + i * 1024);
    }
#pragma unroll
    for (int i = 0; i < 4; i++) {
        const int dd = srow + i * 4;
        load_lds16(Vtbase + (size_t)dd * (MROWS * 2) + (scp ^ ((dd & 15) << 4)),
                   (char*)Vts[0] + wid * 4096 + i * 1024);
    }
    asm volatile("s_waitcnt vmcnt(0)" ::: "memory");
    __builtin_amdgcn_s_barrier();
    __builtin_amdgcn_sched_barrier(0);

    for (int kt = 0; kt < NT; kt++) {
        const int cur = kt & 1;
        const bool more = (kt + 1) < NT;

        if (more) {
#pragma unroll
            for (int i = 0; i < 4; i++) {
                const int rr = srow + i * 4;
                load_lds16(Kbase + (size_t)((kt + 1) * 128 + rr) * (DMODEL * 2) + (scp ^ ((rr & 15) << 4)),
                           (char*)Ks[cur ^ 1] + wid * 4096 + i * 1024);
            }
#pragma unroll
            for (int i = 0; i < 4; i++) {
                const int dd = srow + i * 4;
                load_lds16(Vtbase + (size_t)dd * (MROWS * 2) + (kt + 1) * 256 + (scp ^ ((dd & 15) << 4)),
                           (char*)Vts[cur ^ 1] + wid * 4096 + i * 1024);
            }
        }

        f32x16 sc[2];
        bf16x8 pa[8];

        sc[0] = (f32x16){};
        __builtin_amdgcn_s_setprio(1);
#pragma unroll
        for (int dk = 0; dk < 8; dk++) {
            const int r = 0 * 32 + lo;
            const int cb = (dk * 32 + hi1 * 16) ^ ((r & 15) << 4);
            bf16x8 kf = *(const bf16x8*)((char*)Ks[cur] + r * 256 + cb);
            sc[0] = MFMA32(kf, qf[dk], sc[0]);
        }
        __builtin_amdgcn_s_setprio(0);

#pragma unroll
        for (int g = 0; g < 4; g++) {
            if (g < 3) {
                sc[(g + 1) & 1] = (f32x16){};
                __builtin_amdgcn_s_setprio(1);
#pragma unroll
                for (int dk = 0; dk < 8; dk++) {
                    const int r = (g + 1) * 32 + lo;
                    const int cb = (dk * 32 + hi1 * 16) ^ ((r & 15) << 4);
                    bf16x8 kf = *(const bf16x8*)((char*)Ks[cur] + r * 256 + cb);
                    sc[(g + 1) & 1] = MFMA32(kf, qf[dk], sc[(g + 1) & 1]);
                }
                __builtin_amdgcn_s_setprio(0);
            }
            {
                f32x16& s = sc[g & 1];
#pragma unroll
                for (int r = 0; r < 16; r++)
                    s[r] = exp2_fast(s[r] - C12);
                float s0 = 0.f, s1 = 0.f, s2 = 0.f, s3 = 0.f;
#pragma unroll
                for (int r = 0; r < 16; r += 4) {
                    s0 += s[r]; s1 += s[r + 1]; s2 += s[r + 2]; s3 += s[r + 3];
                }
                lsum += (s0 + s1) + (s2 + s3);
#pragma unroll
                for (int hf = 0; hf < 2; hf++) {
                    const int X0 = cvt_pk_bf16(s[8 * hf + 0], s[8 * hf + 1]);
                    const int X1 = cvt_pk_bf16(s[8 * hf + 2], s[8 * hf + 3]);
                    const int X2 = cvt_pk_bf16(s[8 * hf + 4], s[8 * hf + 5]);
                    const int X3 = cvt_pk_bf16(s[8 * hf + 6], s[8 * hf + 7]);
                    const int L0 = hi1 ? X2 : X0, L1 = hi1 ? X3 : X1;
                    const int S0 = hi1 ? X0 : X2, S1 = hi1 ? X1 : X3;
                    const int R0 = __shfl_xor(S0, 32, 64);
                    const int R1 = __shfl_xor(S1, 32, 64);
                    union { int i[4]; bf16x8 v; } u;
                    u.i[0] = hi1 ? R0 : L0;
                    u.i[1] = hi1 ? R1 : L1;
                    u.i[2] = hi1 ? L0 : R0;
                    u.i[3] = hi1 ? L1 : R1;
                    pa[2 * g + hf] = u.v;
                }
            }
        }

        __builtin_amdgcn_s_setprio(1);
#pragma unroll
        for (int ks = 0; ks < 8; ks++) {
#pragma unroll
            for (int n = 0; n < 4; n++) {
                const int d = n * 32 + lo;
                const int cb = (ks * 32 + hi1 * 16) ^ ((d & 15) << 4);
                bf16x8 vf = *(const bf16x8*)((char*)Vts[cur] + d * 256 + cb);
                oacc[n] = MFMA32(vf, pa[ks], oacc[n]);
            }
        }
        __builtin_amdgcn_s_setprio(0);

        if (more) {
            asm volatile("s_waitcnt vmcnt(0)" ::: "memory");
            asm volatile("s_waitcnt lgkmcnt(0)" ::: "memory");
            __builtin_amdgcn_s_barrier();
            __builtin_amdgcn_sched_barrier(0);
        }
    }

    const float l = lsum + __shfl_xor(lsum, 32, 64);
    const float inv = 1.0f / l;
    short* obase = Oout + (size_t)(b * SEQ + qt * 256 + wid * 32 + lo) * DMODEL + h * DK;
#pragma unroll
    for (int n = 0; n < 4; n++) {
#pragma unroll
        for (int rr = 0; rr < 8; rr++) {
            const int d = n * 32 + 2 * (rr & 1) + 8 * (rr >> 1) + 4 * hi1;
            const int pkv = cvt_pk_bf16(oacc[n][2 * rr] * inv, oacc[n][2 * rr + 1] * inv);
            *(int*)(obase + d) = pkv;
        }
    }
}

// ---------------------------------------------------------------------------
extern "C" void kernel_launch(void* const* d_in, const int* in_sizes, int n_in,
                              void* d_out, int out_size, void* d_ws, size_t ws_size,
                              hipStream_t stream) {
    const float* q   = (const float*)d_in[0];
    const float* k   = (const float*)d_in[1];
    const float* v   = (const float*)d_in[2];
    const float* w_q = (const float*)d_in[3];
    const float* b_q = (const float*)d_in[4];
    const float* w_k = (const float*)d_in[5];
    const float* b_k = (const float*)d_in[6];
    const float* w_v = (const float*)d_in[7];
    const float* b_v = (const float*)d_in[8];
    const float* w_o = (const float*)d_in[9];
    const float* b_o = (const float*)d_in[10];
    float* out = (float*)d_out;

    const size_t PROJ = (size_t)MROWS * DMODEL;
    const size_t WSZ = (size_t)DMODEL * DMODEL;
    // 1/sqrt(128) * log2(e): exp2-based softmax
    const float qscale = 0.08838834764831845f * 1.4426950408889634f;
    const int attn_grid = BATCH * HEADS * (SEQ / 256);  // 512

    if (ws_size >= (6 * PROJ + 4 * WSZ) * sizeof(short)) {
        short* qbf = (short*)d_ws;
        short* kbf = qbf + PROJ;
        short* vbf = kbf + PROJ;
        short* Qp  = vbf + PROJ;
        short* Kp  = Qp + PROJ;
        short* Vt  = Kp + PROJ;   // V^T [DMODEL][MROWS]
        short* wtq = Vt + PROJ;
        short* wtk = wtq + WSZ;
        short* wtv = wtk + WSZ;
        short* wto = wtv + WSZ;
        short* Ao  = qbf;  // reuse (qbf dead after Q projection)

        const int n8 = (int)(PROJ / 8);
        dim3 gcv(32, 32, 7);
        cvt_all<<<gcv, 256, 0, stream>>>(q, k, v, qbf, kbf, vbf,
                                         w_q, w_k, w_v, w_o, wtq, wtk, wtv, wto, n8);

        // fused QKV projections: 768 blocks (tensor-major)
        gemm8_qkv<<<768, 512, 0, stream>>>(qbf, kbf, vbf, wtq, wtk, wtv,
                                           b_q, b_k, b_v, Qp, Kp, Vt, qscale);

        attn_kernel<<<attn_grid, 512, 0, stream>>>(Qp, Kp, Vt, Ao);

        gemm8_one<float><<<256, 512, 0, stream>>>(Ao, wto, b_o, out, 1.0f);
    } else {
        // fallback: 5 x PROJ layout (Qp,Kp,Vp,Vt,Ao)
        short* Qp = (short*)d_ws;
        short* Kp = Qp + PROJ;
        short* Vp = Kp + PROJ;
        short* Vt = Vp + PROJ;
        short* Ao = Vt + PROJ;
        dim3 gblk(DMODEL / 128, MROWS / 128);
        gemm_kernel<float, short><<<gblk, 256, 0, stream>>>(q, w_q, b_q, Qp, qscale);
        gemm_kernel<float, short><<<gblk, 256, 0, stream>>>(k, w_k, b_k, Kp, 1.0f);
        gemm_kernel<float, short><<<gblk, 256, 0, stream>>>(v, w_v, b_v, Vp, 1.0f);
        dim3 gtrv(DMODEL / 64, MROWS / 64);
        tr_bf16<<<gtrv, 256, 0, stream>>>(Vp, Vt);
        attn_kernel<<<attn_grid, 512, 0, stream>>>(Qp, Kp, Vt, Ao);
        gemm_kernel<short, float><<<gblk, 256, 0, stream>>>(Ao, w_o, b_o, out, 1.0f);
    }
}

// Round 15
// 523.984 us; speedup vs baseline: 1.0964x; 1.0022x over previous
//
#include <hip/hip_runtime.h>
#include <hip/hip_bf16.h>

#define DMODEL 2048
#define HEADS 16
#define DK 128
#define BATCH 4
#define SEQ 2048
#define MROWS (BATCH * SEQ)  // 8192

typedef __attribute__((ext_vector_type(8))) short bf16x8;
typedef __attribute__((ext_vector_type(4))) short bf16x4;
typedef __attribute__((ext_vector_type(4))) float f32x4;
typedef __attribute__((ext_vector_type(16))) float f32x16;

static __device__ __forceinline__ short f2bf(float x) {
    __hip_bfloat16 h = __float2bfloat16(x);
    union { __hip_bfloat16 h; short s; } u;
    u.h = h;
    return u.s;
}

static __device__ __forceinline__ int cvt_pk_bf16(float lo, float hi) {
    int r;
    asm("v_cvt_pk_bf16_f32 %0, %1, %2" : "=v"(r) : "v"(lo), "v"(hi));
    return r;
}

static __device__ __forceinline__ float exp2_fast(float x) {
    float r;
    asm("v_exp_f32 %0, %1" : "=v"(r) : "v"(x));
    return r;
}

#define MFMA16(a, b, c) __builtin_amdgcn_mfma_f32_16x16x32_bf16((a), (b), (c), 0, 0, 0)
#define MFMA32(a, b, c) __builtin_amdgcn_mfma_f32_32x32x16_bf16((a), (b), (c), 0, 0, 0)

static __device__ __forceinline__ void load_lds16(const void* g, void* l) {
    __builtin_amdgcn_global_load_lds(
        (const __attribute__((address_space(1))) unsigned int*)g,
        (__attribute__((address_space(3))) unsigned int*)l, 16, 0, 0);
}

// ---------------------------------------------------------------------------
// Fused converts (one dispatch): z in 0..2 -> fp32->bf16 elementwise (q,k,v);
// z in 3..6 -> fp32 [K][N] -> bf16 [N][K] weight transpose (wq,wk,wv,wo).
// ---------------------------------------------------------------------------
__global__ __launch_bounds__(256) void cvt_all(
    const float* __restrict__ i0, const float* __restrict__ i1,
    const float* __restrict__ i2, short* __restrict__ o0,
    short* __restrict__ o1, short* __restrict__ o2,
    const float* __restrict__ w0, const float* __restrict__ w1,
    const float* __restrict__ w2, const float* __restrict__ w3,
    short* __restrict__ t0, short* __restrict__ t1,
    short* __restrict__ t2, short* __restrict__ t3, int n8) {
    const int z = blockIdx.z;
    const int tid = threadIdx.x;
    if (z < 3) {
        const float* in = z == 0 ? i0 : (z == 1 ? i1 : i2);
        short* out = z == 0 ? o0 : (z == 1 ? o1 : o2);
        const int lb = blockIdx.y * 32 + blockIdx.x;  // 0..1023
        int i = lb * 256 + tid;
        const int stride = 1024 * 256;
        for (; i < n8; i += stride) {
            f32x4 a = ((const f32x4*)in)[i * 2];
            f32x4 b = ((const f32x4*)in)[i * 2 + 1];
            bf16x8 o;
            o[0] = f2bf(a[0]); o[1] = f2bf(a[1]); o[2] = f2bf(a[2]); o[3] = f2bf(a[3]);
            o[4] = f2bf(b[0]); o[5] = f2bf(b[1]); o[6] = f2bf(b[2]); o[7] = f2bf(b[3]);
            ((bf16x8*)out)[i] = o;
        }
    } else {
        __shared__ short t[64][72];
        const int which = z - 3;
        const float* W = which == 0 ? w0 : (which == 1 ? w1 : (which == 2 ? w2 : w3));
        short* Wt = which == 0 ? t0 : (which == 1 ? t1 : (which == 2 ? t2 : t3));
        const int n0 = blockIdx.x * 64, k0 = blockIdx.y * 64;
#pragma unroll
        for (int p = 0; p < 4; p++) {
            const int kr = p * 16 + (tid >> 4);
            const int nc = (tid & 15) * 4;
            f32x4 v = *(const f32x4*)&W[(size_t)(k0 + kr) * DMODEL + n0 + nc];
#pragma unroll
            for (int j = 0; j < 4; j++) t[nc + j][kr] = f2bf(v[j]);
        }
        __syncthreads();
        const int nr = tid >> 2, ch = (tid & 3) * 16;
        *(bf16x8*)&Wt[(size_t)(n0 + nr) * DMODEL + k0 + ch] = *(const bf16x8*)&t[nr][ch];
        *(bf16x8*)&Wt[(size_t)(n0 + nr) * DMODEL + k0 + ch + 8] = *(const bf16x8*)&t[nr][ch + 8];
    }
}

// ---------------------------------------------------------------------------
// bf16 [MROWS][DMODEL] -> bf16 [DMODEL][MROWS] transpose (fallback path only)
// ---------------------------------------------------------------------------
__global__ __launch_bounds__(256) void tr_bf16(const short* __restrict__ in,
                                               short* __restrict__ out) {
    __shared__ short t[64][65];
    const int c0 = blockIdx.x * 64, r0 = blockIdx.y * 64;
    const int tid = threadIdx.x;
    const int row = tid >> 2, cb = (tid & 3) * 16;
    bf16x8 a = *(const bf16x8*)&in[(size_t)(r0 + row) * DMODEL + c0 + cb];
    bf16x8 b2 = *(const bf16x8*)&in[(size_t)(r0 + row) * DMODEL + c0 + cb + 8];
#pragma unroll
    for (int j = 0; j < 8; j++) { t[cb + j][row] = a[j]; t[cb + 8 + j][row] = b2[j]; }
    __syncthreads();
#pragma unroll
    for (int j = 0; j < 16; j++)
        out[(size_t)(c0 + row) * MROWS + r0 + cb + j] = t[row][cb + j];
}

// ---------------------------------------------------------------------------
// gemm8 core (verified 4-phase 256x256 schedule): BK=64, 8 waves (2Mx4N),
// single 64KB LDS buffer, counted vmcnt, region-rotated staging.
// Epilogue: simple scalar row-major stores (round-13 form; the lane-pair
// packed variant regressed — split store segments defeated write-combine).
// ---------------------------------------------------------------------------
static __device__ __forceinline__ void stage2(const char* gbase, char* lbase,
                                              int rb, int r8, int scol, int ktb) {
#pragma unroll
    for (int i = 0; i < 2; i++)
        load_lds16(gbase + (size_t)(rb + i * 8 + r8) * (DMODEL * 2) + ktb + scol,
                   lbase + (rb + i * 8) * 128);
}

template <typename OT>
static __device__ __forceinline__ void gemm8_impl(
    char* Asl, char* Bsl,
    const short* __restrict__ A, const short* __restrict__ Bt,
    const float* __restrict__ bias, OT* __restrict__ C,
    float oscale, bool transv, int bx, int by) {
    const int tid = threadIdx.x, lane = tid & 63, wid = tid >> 6;
    const int row0 = by * 256, col0 = bx * 256;
    const int wm = wid >> 2, wn = wid & 3;

    const int r8 = lane >> 3;
    const int scol = ((lane & 7) * 16) ^ (r8 << 4);
    const int a1r = ((wid & 4) << 5) + (wid & 3) * 16;
    const int b1r = (wid >> 1) * 64 + (wid & 1) * 16;

    const char* Ab = (const char*)A + (size_t)row0 * (DMODEL * 2);
    const char* Bb = (const char*)Bt + (size_t)col0 * (DMODEL * 2);

    const int arow = wm * 128 + (lane & 15);
    const int brow = wn * 64 + (lane & 15);
    const int fg = (lane >> 4) * 16;
    const int fx = (lane & 7) << 4;

    f32x4 acc[8][4] = {};
    bf16x8 af[4][2], bfr[4][2];

    const int NT = DMODEL / 64;

    stage2(Ab, Asl, a1r, r8, scol, 0);
    stage2(Bb, Bsl, b1r, r8, scol, 0);
    stage2(Bb, Bsl, b1r + 32, r8, scol, 0);
    stage2(Ab, Asl, a1r + 64, r8, scol, 0);

    for (int t = 0; t < NT; t++) {
        const bool more = (t + 1) < NT;
        const int ktb = (t + 1) * 128;

        // phase 0
        asm volatile("s_waitcnt vmcnt(4)" ::: "memory");
        asm volatile("s_waitcnt lgkmcnt(0)" ::: "memory");
        __builtin_amdgcn_s_barrier();
        __builtin_amdgcn_sched_barrier(0);
#pragma unroll
        for (int m = 0; m < 4; m++)
#pragma unroll
            for (int kk = 0; kk < 2; kk++)
                af[m][kk] = *(const bf16x8*)(Asl + (arow + m * 16) * 128 + ((kk * 64 + fg) ^ fx));
#pragma unroll
        for (int n = 0; n < 2; n++)
#pragma unroll
            for (int kk = 0; kk < 2; kk++)
                bfr[n][kk] = *(const bf16x8*)(Bsl + (brow + n * 16) * 128 + ((kk * 64 + fg) ^ fx));
        __builtin_amdgcn_s_setprio(1);
#pragma unroll
        for (int m = 0; m < 4; m++)
#pragma unroll
            for (int n = 0; n < 2; n++)
#pragma unroll
                for (int kk = 0; kk < 2; kk++)
                    acc[m][n] = MFMA16(af[m][kk], bfr[n][kk], acc[m][n]);
        __builtin_amdgcn_s_setprio(0);

        // phase 1
        asm volatile("s_waitcnt vmcnt(2)" ::: "memory");
        asm volatile("s_waitcnt lgkmcnt(0)" ::: "memory");
        __builtin_amdgcn_s_barrier();
        __builtin_amdgcn_sched_barrier(0);
#pragma unroll
        for (int n = 2; n < 4; n++)
#pragma unroll
            for (int kk = 0; kk < 2; kk++)
                bfr[n][kk] = *(const bf16x8*)(Bsl + (brow + n * 16) * 128 + ((kk * 64 + fg) ^ fx));
        if (more) {
            stage2(Ab, Asl, a1r, r8, scol, ktb);
            stage2(Bb, Bsl, b1r, r8, scol, ktb);
        }
        __builtin_amdgcn_s_setprio(1);
#pragma unroll
        for (int m = 0; m < 4; m++)
#pragma unroll
            for (int n = 2; n < 4; n++)
#pragma unroll
                for (int kk = 0; kk < 2; kk++)
                    acc[m][n] = MFMA16(af[m][kk], bfr[n][kk], acc[m][n]);
        __builtin_amdgcn_s_setprio(0);

        // phase 2
        if (more) asm volatile("s_waitcnt vmcnt(4)" ::: "memory");
        else      asm volatile("s_waitcnt vmcnt(0)" ::: "memory");
        asm volatile("s_waitcnt lgkmcnt(0)" ::: "memory");
        __builtin_amdgcn_s_barrier();
        __builtin_amdgcn_sched_barrier(0);
#pragma unroll
        for (int mi = 0; mi < 4; mi++)
#pragma unroll
            for (int kk = 0; kk < 2; kk++)
                af[mi][kk] = *(const bf16x8*)(Asl + (arow + 64 + mi * 16) * 128 + ((kk * 64 + fg) ^ fx));
        if (more) stage2(Bb, Bsl, b1r + 32, r8, scol, ktb);
        __builtin_amdgcn_s_setprio(1);
#pragma unroll
        for (int mi = 0; mi < 4; mi++)
#pragma unroll
            for (int n = 2; n < 4; n++)
#pragma unroll
                for (int kk = 0; kk < 2; kk++)
                    acc[4 + mi][n] = MFMA16(af[mi][kk], bfr[n][kk], acc[4 + mi][n]);
        __builtin_amdgcn_s_setprio(0);

        // phase 3
        asm volatile("s_waitcnt lgkmcnt(0)" ::: "memory");
        __builtin_amdgcn_s_barrier();
        __builtin_amdgcn_sched_barrier(0);
        if (more) stage2(Ab, Asl, a1r + 64, r8, scol, ktb);
        __builtin_amdgcn_s_setprio(1);
#pragma unroll
        for (int mi = 0; mi < 4; mi++)
#pragma unroll
            for (int n = 0; n < 2; n++)
#pragma unroll
                for (int kk = 0; kk < 2; kk++)
                    acc[4 + mi][n] = MFMA16(af[mi][kk], bfr[n][kk], acc[4 + mi][n]);
        __builtin_amdgcn_s_setprio(0);
    }

    // ---- epilogue (simple scalar, round-13 form) ----
#pragma unroll
    for (int n = 0; n < 4; n++) {
        const int col = col0 + wn * 64 + n * 16 + (lane & 15);
        const float bz = bias[col];
#pragma unroll
        for (int m = 0; m < 8; m++) {
            const int row4 = row0 + wm * 128 + m * 16 + (lane >> 4) * 4;
            if (transv) {
                bf16x4 tv;
#pragma unroll
                for (int j = 0; j < 4; j++) tv[j] = f2bf((acc[m][n][j] + bz) * oscale);
                *(bf16x4*)&((short*)C)[(size_t)col * MROWS + row4] = tv;
            } else {
#pragma unroll
                for (int j = 0; j < 4; j++) {
                    const float v = (acc[m][n][j] + bz) * oscale;
                    if constexpr (sizeof(OT) == 2)
                        C[(size_t)(row4 + j) * DMODEL + col] = (OT)f2bf(v);
                    else
                        C[(size_t)(row4 + j) * DMODEL + col] = (OT)v;
                }
            }
        }
    }
}

// single-GEMM launcher (O projection): grid 256
template <typename OT>
__global__ __launch_bounds__(512, 2) void gemm8_one(
    const short* __restrict__ A, const short* __restrict__ Bt,
    const float* __restrict__ bias, OT* __restrict__ C, float oscale) {
    __shared__ short Asl[256 * 64];
    __shared__ short Bsl[256 * 64];
    const int nwg = gridDim.x;
    const int bid = blockIdx.x;
    const int swz = (bid & 7) * (nwg >> 3) + (bid >> 3);
    const int bx = swz >> 5, by = swz & 31;
    gemm8_impl<OT>((char*)Asl, (char*)Bsl, A, Bt, bias, C, oscale, false, bx, by);
}

// fused QKV launcher: grid 768 = 3 x 256 (tensor-major block order)
__global__ __launch_bounds__(512, 2) void gemm8_qkv(
    const short* __restrict__ qA, const short* __restrict__ kA,
    const short* __restrict__ vA, const short* __restrict__ wq,
    const short* __restrict__ wk, const short* __restrict__ wv,
    const float* __restrict__ bq, const float* __restrict__ bk,
    const float* __restrict__ bv, short* __restrict__ Qp,
    short* __restrict__ Kp, short* __restrict__ Vt, float qscale) {
    __shared__ short Asl[256 * 64];
    __shared__ short Bsl[256 * 64];
    const int bid = blockIdx.x;
    const int which = bid >> 8;       // 0=q 1=k 2=v
    const int lb = bid & 255;
    const int swz = (lb & 7) * 32 + (lb >> 3);
    const int bx = swz >> 5, by = swz & 31;
    const short* A = which == 0 ? qA : (which == 1 ? kA : vA);
    const short* Bt = which == 0 ? wq : (which == 1 ? wk : wv);
    const float* bias = which == 0 ? bq : (which == 1 ? bk : bv);
    short* C = which == 0 ? Qp : (which == 1 ? Kp : Vt);
    const float os = which == 0 ? qscale : 1.0f;
    gemm8_impl<short>((char*)Asl, (char*)Bsl, A, Bt, bias, C, os, which == 2, bx, by);
}

// ---------------------------------------------------------------------------
// Fallback GEMM (round-0): A fp32 or bf16, conversion in staging.
// ---------------------------------------------------------------------------
template <typename AT, typename OT>
__global__ __launch_bounds__(256) void gemm_kernel(
    const AT* __restrict__ A, const float* __restrict__ W,
    const float* __restrict__ bias, OT* __restrict__ C, float oscale) {
    const int K = DMODEL, N = DMODEL;
    __shared__ short As[128][40];
    __shared__ short Bs[128][40];
    const int tid = threadIdx.x;
    const int lane = tid & 63;
    const int wid = tid >> 6;
    const int wm = wid >> 1, wn = wid & 1;
    const int row0 = blockIdx.y * 128;
    const int col0 = blockIdx.x * 128;
    f32x4 acc[4][4] = {};
    const int a_row = tid >> 1;
    const int a_col = (tid & 1) * 16;
    const int b_n = (tid & 31) * 4;
    const int b_k = (tid >> 5) * 4;
    for (int k0 = 0; k0 < K; k0 += 32) {
        __syncthreads();
        {
            const AT* src = A + (size_t)(row0 + a_row) * K + k0 + a_col;
            if constexpr (sizeof(AT) == 4) {
                const float* sf = reinterpret_cast<const float*>(src);
                f32x4 v0 = *(const f32x4*)(sf + 0);
                f32x4 v1 = *(const f32x4*)(sf + 4);
                f32x4 v2 = *(const f32x4*)(sf + 8);
                f32x4 v3 = *(const f32x4*)(sf + 12);
                bf16x8 w0, w1;
                w0[0] = f2bf(v0[0]); w0[1] = f2bf(v0[1]); w0[2] = f2bf(v0[2]); w0[3] = f2bf(v0[3]);
                w0[4] = f2bf(v1[0]); w0[5] = f2bf(v1[1]); w0[6] = f2bf(v1[2]); w0[7] = f2bf(v1[3]);
                w1[0] = f2bf(v2[0]); w1[1] = f2bf(v2[1]); w1[2] = f2bf(v2[2]); w1[3] = f2bf(v2[3]);
                w1[4] = f2bf(v3[0]); w1[5] = f2bf(v3[1]); w1[6] = f2bf(v3[2]); w1[7] = f2bf(v3[3]);
                *(bf16x8*)&As[a_row][a_col + 0] = w0;
                *(bf16x8*)&As[a_row][a_col + 8] = w1;
            } else {
                const short* ss = reinterpret_cast<const short*>(src);
                *(bf16x8*)&As[a_row][a_col + 0] = *(const bf16x8*)(ss + 0);
                *(bf16x8*)&As[a_row][a_col + 8] = *(const bf16x8*)(ss + 8);
            }
        }
        {
            const float* w0p = W + (size_t)(k0 + b_k + 0) * N + col0 + b_n;
            f32x4 r0 = *(const f32x4*)(w0p);
            f32x4 r1 = *(const f32x4*)(w0p + N);
            f32x4 r2 = *(const f32x4*)(w0p + 2 * N);
            f32x4 r3 = *(const f32x4*)(w0p + 3 * N);
#pragma unroll
            for (int j = 0; j < 4; j++) {
                bf16x4 t;
                t[0] = f2bf(r0[j]); t[1] = f2bf(r1[j]); t[2] = f2bf(r2[j]); t[3] = f2bf(r3[j]);
                *(bf16x4*)&Bs[b_n + j][b_k] = t;
            }
        }
        __syncthreads();
        bf16x8 af[4], bfr[4];
#pragma unroll
        for (int m = 0; m < 4; m++)
            af[m] = *(const bf16x8*)&As[wm * 64 + m * 16 + (lane & 15)][(lane >> 4) * 8];
#pragma unroll
        for (int n = 0; n < 4; n++)
            bfr[n] = *(const bf16x8*)&Bs[wn * 64 + n * 16 + (lane & 15)][(lane >> 4) * 8];
#pragma unroll
        for (int m = 0; m < 4; m++)
#pragma unroll
            for (int n = 0; n < 4; n++)
                acc[m][n] = MFMA16(af[m], bfr[n], acc[m][n]);
    }
#pragma unroll
    for (int m = 0; m < 4; m++) {
#pragma unroll
        for (int n = 0; n < 4; n++) {
            const int col = col0 + wn * 64 + n * 16 + (lane & 15);
            const float bz = bias[col];
#pragma unroll
            for (int j = 0; j < 4; j++) {
                const int row = row0 + wm * 64 + m * 16 + (lane >> 4) * 4 + j;
                const float v = (acc[m][n][j] + bz) * oscale;
                if constexpr (sizeof(OT) == 2)
                    C[(size_t)row * N + col] = (OT)f2bf(v);
                else
                    C[(size_t)row * N + col] = (OT)v;
            }
        }
    }
}

// ---------------------------------------------------------------------------
// Flash attention v9 (unchanged): 8 waves, QBLK=256, KVBLK=128, in-register
// softmax, conflict-free swizzle, K/V^T via global_load_lds, kg-pipelined.
// ---------------------------------------------------------------------------
__global__ __launch_bounds__(512, 2) void attn_kernel(
    const short* __restrict__ Qp, const short* __restrict__ Kp,
    const short* __restrict__ Vtp, short* __restrict__ Oout) {
    const int nwg = gridDim.x;
    const int bid = blockIdx.x;
    const int bx = (bid & 7) * (nwg >> 3) + (bid >> 3);
    const int qt = bx & 7;            // SEQ/256 = 8
    const int h = (bx >> 3) & 15;
    const int b = bx >> 7;

    __shared__ short Ks[2][128 * 128];   // [key][d], 256B rows, XOR (key&15)<<4
    __shared__ short Vts[2][128 * 128];  // [d][key], 256B rows, XOR (d&15)<<4

    const int tid = threadIdx.x;
    const int lane = tid & 63;
    const int wid = tid >> 6;           // 0..7
    const int lo = lane & 31;
    const int hi1 = lane >> 5;

    bf16x8 qf[8];
    {
        const short* qrow = Qp + (size_t)(b * SEQ + qt * 256 + wid * 32 + lo) * DMODEL + h * DK;
#pragma unroll
        for (int dk = 0; dk < 8; dk++)
            qf[dk] = *(const bf16x8*)(qrow + dk * 16 + hi1 * 8);
    }

    f32x16 oacc[4] = {};
    float lsum = 0.f;

    const char* Kbase = (const char*)(Kp + (size_t)(b * SEQ) * DMODEL + h * DK);
    const char* Vtbase = (const char*)(Vtp + (size_t)(h * DK) * MROWS + b * SEQ);

    const int srow = wid * 16 + (lane >> 4);
    const int scp = (lane & 15) * 16;
    const int NT = SEQ / 128;                   // 16
    const float C12 = 17.3123404906676f;        // 12 * log2(e)

#pragma unroll
    for (int i = 0; i < 4; i++) {
        const int rr = srow + i * 4;
        load_lds16(Kbase + (size_t)rr * (DMODEL * 2) + (scp ^ ((rr & 15) << 4)),
                   (char*)Ks[0] + wid * 4096 + i * 1024);
    }
#pragma unroll
    for (int i = 0; i < 4; i++) {
        const int dd = srow + i * 4;
        load_lds16(Vtbase + (size_t)dd * (MROWS * 2) + (scp ^ ((dd & 15) << 4)),
                   (char*)Vts[0] + wid * 4096 + i * 1024);
    }
    asm volatile("s_waitcnt vmcnt(0)" ::: "memory");
    __builtin_amdgcn_s_barrier();
    __builtin_amdgcn_sched_barrier(0);

    for (int kt = 0; kt < NT; kt++) {
        const int cur = kt & 1;
        const bool more = (kt + 1) < NT;

        if (more) {
#pragma unroll
            for (int i = 0; i < 4; i++) {
                const int rr = srow + i * 4;
                load_lds16(Kbase + (size_t)((kt + 1) * 128 + rr) * (DMODEL * 2) + (scp ^ ((rr & 15) << 4)),
                           (char*)Ks[cur ^ 1] + wid * 4096 + i * 1024);
            }
#pragma unroll
            for (int i = 0; i < 4; i++) {
                const int dd = srow + i * 4;
                load_lds16(Vtbase + (size_t)dd * (MROWS * 2) + (kt + 1) * 256 + (scp ^ ((dd & 15) << 4)),
                           (char*)Vts[cur ^ 1] + wid * 4096 + i * 1024);
            }
        }

        f32x16 sc[2];
        bf16x8 pa[8];

        sc[0] = (f32x16){};
        __builtin_amdgcn_s_setprio(1);
#pragma unroll
        for (int dk = 0; dk < 8; dk++) {
            const int r = 0 * 32 + lo;
            const int cb = (dk * 32 + hi1 * 16) ^ ((r & 15) << 4);
            bf16x8 kf = *(const bf16x8*)((char*)Ks[cur] + r * 256 + cb);
            sc[0] = MFMA32(kf, qf[dk], sc[0]);
        }
        __builtin_amdgcn_s_setprio(0);

#pragma unroll
        for (int g = 0; g < 4; g++) {
            if (g < 3) {
                sc[(g + 1) & 1] = (f32x16){};
                __builtin_amdgcn_s_setprio(1);
#pragma unroll
                for (int dk = 0; dk < 8; dk++) {
                    const int r = (g + 1) * 32 + lo;
                    const int cb = (dk * 32 + hi1 * 16) ^ ((r & 15) << 4);
                    bf16x8 kf = *(const bf16x8*)((char*)Ks[cur] + r * 256 + cb);
                    sc[(g + 1) & 1] = MFMA32(kf, qf[dk], sc[(g + 1) & 1]);
                }
                __builtin_amdgcn_s_setprio(0);
            }
            {
                f32x16& s = sc[g & 1];
#pragma unroll
                for (int r = 0; r < 16; r++)
                    s[r] = exp2_fast(s[r] - C12);
                float s0 = 0.f, s1 = 0.f, s2 = 0.f, s3 = 0.f;
#pragma unroll
                for (int r = 0; r < 16; r += 4) {
                    s0 += s[r]; s1 += s[r + 1]; s2 += s[r + 2]; s3 += s[r + 3];
                }
                lsum += (s0 + s1) + (s2 + s3);
#pragma unroll
                for (int hf = 0; hf < 2; hf++) {
                    const int X0 = cvt_pk_bf16(s[8 * hf + 0], s[8 * hf + 1]);
                    const int X1 = cvt_pk_bf16(s[8 * hf + 2], s[8 * hf + 3]);
                    const int X2 = cvt_pk_bf16(s[8 * hf + 4], s[8 * hf + 5]);
                    const int X3 = cvt_pk_bf16(s[8 * hf + 6], s[8 * hf + 7]);
                    const int L0 = hi1 ? X2 : X0, L1 = hi1 ? X3 : X1;
                    const int S0 = hi1 ? X0 : X2, S1 = hi1 ? X1 : X3;
                    const int R0 = __shfl_xor(S0, 32, 64);
                    const int R1 = __shfl_xor(S1, 32, 64);
                    union { int i[4]; bf16x8 v; } u;
                    u.i[0] = hi1 ? R0 : L0;
                    u.i[1] = hi1 ? R1 : L1;
                    u.i[2] = hi1 ? L0 : R0;
                    u.i[3] = hi1 ? L1 : R1;
                    pa[2 * g + hf] = u.v;
                }
            }
        }

        __builtin_amdgcn_s_setprio(1);
#pragma unroll
        for (int ks = 0; ks < 8; ks++) {
#pragma unroll
            for (int n = 0; n < 4; n++) {
                const int d = n * 32 + lo;
                const int cb = (ks * 32 + hi1 * 16) ^ ((d & 15) << 4);
                bf16x8 vf = *(const bf16x8*)((char*)Vts[cur] + d * 256 + cb);
                oacc[n] = MFMA32(vf, pa[ks], oacc[n]);
            }
        }
        __builtin_amdgcn_s_setprio(0);

        if (more) {
            asm volatile("s_waitcnt vmcnt(0)" ::: "memory");
            asm volatile("s_waitcnt lgkmcnt(0)" ::: "memory");
            __builtin_amdgcn_s_barrier();
            __builtin_amdgcn_sched_barrier(0);
        }
    }

    const float l = lsum + __shfl_xor(lsum, 32, 64);
    const float inv = 1.0f / l;
    short* obase = Oout + (size_t)(b * SEQ + qt * 256 + wid * 32 + lo) * DMODEL + h * DK;
#pragma unroll
    for (int n = 0; n < 4; n++) {
#pragma unroll
        for (int rr = 0; rr < 8; rr++) {
            const int d = n * 32 + 2 * (rr & 1) + 8 * (rr >> 1) + 4 * hi1;
            const int pkv = cvt_pk_bf16(oacc[n][2 * rr] * inv, oacc[n][2 * rr + 1] * inv);
            *(int*)(obase + d) = pkv;
        }
    }
}

// ---------------------------------------------------------------------------
extern "C" void kernel_launch(void* const* d_in, const int* in_sizes, int n_in,
                              void* d_out, int out_size, void* d_ws, size_t ws_size,
                              hipStream_t stream) {
    const float* q   = (const float*)d_in[0];
    const float* k   = (const float*)d_in[1];
    const float* v   = (const float*)d_in[2];
    const float* w_q = (const float*)d_in[3];
    const float* b_q = (const float*)d_in[4];
    const float* w_k = (const float*)d_in[5];
    const float* b_k = (const float*)d_in[6];
    const float* w_v = (const float*)d_in[7];
    const float* b_v = (const float*)d_in[8];
    const float* w_o = (const float*)d_in[9];
    const float* b_o = (const float*)d_in[10];
    float* out = (float*)d_out;

    const size_t PROJ = (size_t)MROWS * DMODEL;
    const size_t WSZ = (size_t)DMODEL * DMODEL;
    // 1/sqrt(128) * log2(e): exp2-based softmax
    const float qscale = 0.08838834764831845f * 1.4426950408889634f;
    const int attn_grid = BATCH * HEADS * (SEQ / 256);  // 512

    if (ws_size >= (6 * PROJ + 4 * WSZ) * sizeof(short)) {
        short* qbf = (short*)d_ws;
        short* kbf = qbf + PROJ;
        short* vbf = kbf + PROJ;
        short* Qp  = vbf + PROJ;
        short* Kp  = Qp + PROJ;
        short* Vt  = Kp + PROJ;   // V^T [DMODEL][MROWS]
        short* wtq = Vt + PROJ;
        short* wtk = wtq + WSZ;
        short* wtv = wtk + WSZ;
        short* wto = wtv + WSZ;
        short* Ao  = qbf;  // reuse (qbf dead after Q projection)

        const int n8 = (int)(PROJ / 8);
        dim3 gcv(32, 32, 7);
        cvt_all<<<gcv, 256, 0, stream>>>(q, k, v, qbf, kbf, vbf,
                                         w_q, w_k, w_v, w_o, wtq, wtk, wtv, wto, n8);

        // fused QKV projections: 768 blocks (tensor-major)
        gemm8_qkv<<<768, 512, 0, stream>>>(qbf, kbf, vbf, wtq, wtk, wtv,
                                           b_q, b_k, b_v, Qp, Kp, Vt, qscale);

        attn_kernel<<<attn_grid, 512, 0, stream>>>(Qp, Kp, Vt, Ao);

        gemm8_one<float><<<256, 512, 0, stream>>>(Ao, wto, b_o, out, 1.0f);
    } else {
        // fallback: 5 x PROJ layout (Qp,Kp,Vp,Vt,Ao)
        short* Qp = (short*)d_ws;
        short* Kp = Qp + PROJ;
        short* Vp = Kp + PROJ;
        short* Vt = Vp + PROJ;
        short* Ao = Vt + PROJ;
        dim3 gblk(DMODEL / 128, MROWS / 128);
        gemm_kernel<float, short><<<gblk, 256, 0, stream>>>(q, w_q, b_q, Qp, qscale);
        gemm_kernel<float, short><<<gblk, 256, 0, stream>>>(k, w_k, b_k, Kp, 1.0f);
        gemm_kernel<float, short><<<gblk, 256, 0, stream>>>(v, w_v, b_v, Vp, 1.0f);
        dim3 gtrv(DMODEL / 64, MROWS / 64);
        tr_bf16<<<gtrv, 256, 0, stream>>>(Vp, Vt);
        attn_kernel<<<attn_grid, 512, 0, stream>>>(Qp, Kp, Vt, Ao);
        gemm_kernel<short, float><<<gblk, 256, 0, stream>>>(Ao, w_o, b_o, out, 1.0f);
    }
}